// Round 4
// baseline (198.900 us; speedup 1.0000x reference)
//
#include <hip/hip_runtime.h>
#include <math.h>

#define THREADS 256
#define GRID 512
#define NRAYS 8192
#define FAR_T 10.0f

typedef __attribute__((ext_vector_type(8))) short short8;
typedef __attribute__((ext_vector_type(4))) float f32x4;

static __device__ __forceinline__ unsigned f2bfu(float f) {
    unsigned u = __builtin_bit_cast(unsigned, f);
    return (u + 0x7fffu + ((u >> 16) & 1u)) >> 16;
}
// fast bf16x2 pack: round-half-up + v_perm_b32 byte select (3 VALU ops)
static __device__ __forceinline__ unsigned pk2(float a, float b) {
    unsigned ra = __builtin_bit_cast(unsigned, a) + 0x8000u;
    unsigned rb = __builtin_bit_cast(unsigned, b) + 0x8000u;
    return __builtin_amdgcn_perm(rb, ra, 0x07060302u);
}
// swizzled short-index for [r][128] bf16 tiles
static __device__ __forceinline__ int sw128(int r, int k) { return (r << 7) + (k ^ ((r & 7) << 3)); }
// swizzled short-index for [r][32] bf16 tiles
static __device__ __forceinline__ int sw32(int r, int k)  { return (r << 5) + (k ^ ((r & 3) << 3)); }
static __device__ __forceinline__ f32x4 MFMA16(short8 a, short8 b, f32x4 c) {
    return __builtin_amdgcn_mfma_f32_16x16x32_bf16(a, b, c, 0, 0, 0);
}

struct RayP { float ox,oy,oz,dx,dy,dz,tn,tf,tstep,dnorm; bool act; };

static __device__ __forceinline__ RayP raySetup(const float* __restrict__ ro, const float* __restrict__ rd,
        int r, float a0x,float a0y,float a0z,float a1x,float a1y,float a1z) {
    RayP R;
    R.ox=ro[3*r+0]; R.oy=ro[3*r+1]; R.oz=ro[3*r+2];
    R.dx=rd[3*r+0]; R.dy=rd[3*r+1]; R.dz=rd[3*r+2];
    float ivx=1.f/R.dx, ivy=1.f/R.dy, ivz=1.f/R.dz;
    float t1x=(a0x-R.ox)*ivx, t2x=(a1x-R.ox)*ivx;
    float t1y=(a0y-R.oy)*ivy, t2y=(a1y-R.oy)*ivy;
    float t1z=(a0z-R.oz)*ivz, t2z=(a1z-R.oz)*ivz;
    float tn = fmaxf(fmaxf(fminf(t1x,t2x),fminf(t1y,t2y)),fminf(t1z,t2z));
    tn = fmaxf(tn, 0.f);
    float tf = fminf(fminf(fmaxf(t1x,t2x),fmaxf(t1y,t2y)),fmaxf(t1z,t2z));
    tf = fminf(tf, FAR_T);
    R.act = tn < tf;
    R.tn = R.act ? tn : 0.f;
    R.tf = R.act ? tf : 1.f;
    R.tstep = (R.tf - R.tn) * (1.f/64.f);
    R.dnorm = sqrtf(R.dx*R.dx + R.dy*R.dy + R.dz*R.dz);
    return R;
}

struct WStage { short W2T[16384]; short WfdT[4096]; short Wc1T[4096]; short Wc2T[2048]; }; // 52 KB
struct Act    { short H1[16384]; short H2[16384]; short CC[4096]; float SIG[128]; float COL[512]; }; // 74.5 KB

__global__ __launch_bounds__(THREADS, 2)
void RadianceRenderer_kernel(const float* __restrict__ rays_o, const float* __restrict__ rays_d,
                             const float* __restrict__ aabb,
                             const float* __restrict__ W1, const float* __restrict__ b1,
                             const float* __restrict__ W2, const float* __restrict__ b2,
                             const float* __restrict__ Wd, const float* __restrict__ bd,
                             const float* __restrict__ Wf, const float* __restrict__ bf,
                             const float* __restrict__ Wc1, const float* __restrict__ bc1,
                             const float* __restrict__ Wc2, const float* __restrict__ bc2,
                             float* __restrict__ out)
{
    __shared__ union { WStage w; Act a; } sm;   // weight staging aliases activations

    const int tid  = threadIdx.x;
    const int lane = tid & 63;
    const int wv   = tid >> 6;
    const int l15  = lane & 15;
    const int l4   = lane >> 4;

    // ---- stage weights (one-time): transpose + bf16 + swizzle ----
    for (int i = tid; i < 128*128; i += THREADS) {
        int k = i >> 7, n = i & 127;
        sm.w.W2T[sw128(n, k)] = (short)f2bfu(W2[i]);
    }
    for (int i = tid; i < 32*128; i += THREADS) {
        int n = i >> 7, k = i & 127;
        float v = (n < 16) ? Wf[k*16 + n] : ((n == 16) ? Wd[k] : 0.f);
        sm.w.WfdT[sw128(n, k)] = (short)f2bfu(v);
    }
    for (int i = tid; i < 128*32; i += THREADS) {
        int n = i >> 5, k = i & 31;
        sm.w.Wc1T[sw32(n, k)] = (short)f2bfu(Wc1[k*128 + n]);
    }
    for (int i = tid; i < 16*128; i += THREADS) {
        int c = i >> 7, k = i & 127;
        float v = (c < 3) ? Wc2[k*3 + c] : 0.f;
        sm.w.Wc2T[sw128(c, k)] = (short)f2bfu(v);
    }
    __syncthreads();

    const int chB = (wv >> 1) * 64;
    const int smB = (wv & 1) * 64;
    const int sB3 = wv * 32;

    short8 w2f[4][4], wfdf[2][4], wc1f[4], wc2f[4], w1f[4];
    #pragma unroll
    for (int jn = 0; jn < 4; ++jn)
        #pragma unroll
        for (int kk = 0; kk < 4; ++kk)
            w2f[jn][kk] = *(const short8*)&sm.w.W2T[sw128(chB + 16*jn + l15, kk*32 + 8*l4)];
    #pragma unroll
    for (int cg = 0; cg < 2; ++cg)
        #pragma unroll
        for (int kk = 0; kk < 4; ++kk)
            wfdf[cg][kk] = *(const short8*)&sm.w.WfdT[sw128(16*cg + l15, kk*32 + 8*l4)];
    #pragma unroll
    for (int cg = 0; cg < 4; ++cg)
        wc1f[cg] = *(const short8*)&sm.w.Wc1T[sw32(chB + 16*cg + l15, 8*l4)];
    #pragma unroll
    for (int kk = 0; kk < 4; ++kk)
        wc2f[kk] = *(const short8*)&sm.w.Wc2T[sw128(l15, kk*32 + 8*l4)];
    // layer-1 extended weight frag from global: rows=out-ch, k=0..2 -> W1, k=3 -> b1, k>=4 -> 0
    #pragma unroll
    for (int jn = 0; jn < 4; ++jn) {
        int ch = chB + 16*jn + l15;
        short8 v;
        #pragma unroll
        for (int e = 0; e < 8; ++e) {
            int k = 8*l4 + e;
            float f = (k < 3) ? W1[k*128 + ch] : ((k == 3) ? b1[ch] : 0.f);
            v[e] = (short)f2bfu(f);
        }
        w1f[jn] = v;
    }

    float b2r[4][4], bc1r[4][4], bfr4[4], bc2r[3];
    #pragma unroll
    for (int jn = 0; jn < 4; ++jn)
        #pragma unroll
        for (int vv = 0; vv < 4; ++vv) {
            b2r[jn][vv]  = b2[chB + 16*jn + 4*l4 + vv];
            bc1r[jn][vv] = bc1[chB + 16*jn + 4*l4 + vv];
        }
    #pragma unroll
    for (int vv = 0; vv < 4; ++vv) bfr4[vv] = bf[4*l4 + vv];
    bc2r[0] = bc2[0]; bc2r[1] = bc2[1]; bc2r[2] = bc2[2];
    const float bdr = bd[0];

    const float a0x=aabb[0],a0y=aabb[1],a0z=aabb[2],a1x=aabb[3],a1y=aabb[4],a1z=aabb[5];
    const float scx=2.f/(a1x-a0x), scy=2.f/(a1y-a0y), scz=2.f/(a1z-a0z);

    __syncthreads();   // all weight-register reads done before Act writes begin

    // zero CC once: L1 reads cols 4..15 before G3' ever writes them; uninitialized
    // LDS could hold NaN bf16 patterns and 0*NaN = NaN in MFMA.
    for (int i = tid; i < 2048; i += THREADS) ((unsigned*)sm.a.CC)[i] = 0u;
    __syncthreads();

    int gp = -1;
    RayP Rp;

    for (int g = blockIdx.x; g < NRAYS/2; g += gridDim.x) {
        // ========== A0 (waves 2,3): xyz rows + ynm rows  ||  F(gp) (waves 0,1) ==========
        if (wv >= 2) {
            const int m   = tid - 128;          // sample row 0..127
            const int ray = 2*g + (m >> 6);
            RayP R = raySetup(rays_o, rays_d, ray, a0x,a0y,a0z,a1x,a1y,a1z);
            const int s = m & 63;
            float t  = R.tn + ((float)s + 0.5f) * R.tstep;
            float px = fmaf(R.dx, t, R.ox);
            float py = fmaf(R.dy, t, R.oy);
            float pz = fmaf(R.dz, t, R.oz);
            float nx = fmaf(px - a0x, scx, -1.f);
            float ny = fmaf(py - a0y, scy, -1.f);
            float nz = fmaf(pz - a0z, scz, -1.f);
            // xyz+1 into CC cols 0..3 (K-junk beyond k=3 is zeroed by w1f)
            *(uint2*)&sm.a.CC[sw32(m, 0)] = make_uint2(pk2(nx, ny), pk2(nz, 1.0f));
            // ynm broadcast into CC cols 16..31 (row-local compute)
            float inorm = 1.f / R.dnorm;
            float x = R.dx*inorm, y = R.dy*inorm, z = R.dz*inorm;
            float x2 = x*x, y2 = y*y, z2 = z*z;
            unsigned q0 = pk2(0.282094791773878f,              -0.488602511902920f*y);
            unsigned q1 = pk2(0.488602511902920f*z,            -0.488602511902920f*x);
            unsigned q2 = pk2(1.092548430592079f*x*y,          -1.092548430592079f*y*z);
            unsigned q3 = pk2(0.315391565252520f*(3.f*z2-1.f), -1.092548430592079f*x*z);
            unsigned q4 = pk2(0.546274215296040f*(x2-y2),      -0.590043589926644f*y*(3.f*x2-y2));
            unsigned q5 = pk2(2.890611442640554f*x*y*z,        -0.457045799464466f*y*(5.f*z2-1.f));
            unsigned q6 = pk2(0.373176332590115f*z*(5.f*z2-3.f), -0.457045799464466f*x*(5.f*z2-1.f));
            unsigned q7 = pk2(1.445305721320277f*z*(x2-y2),    -0.590043589926644f*x*(x2-3.f*y2));
            *(uint4*)&sm.a.CC[sw32(m, 16)] = make_uint4(q0,q1,q2,q3);
            *(uint4*)&sm.a.CC[sw32(m, 24)] = make_uint4(q4,q5,q6,q7);
        } else if (gp >= 0) {
            // ========== F: transmittance integration for previous iteration ==========
            const RayP R = Rp;
            const int m = wv*64 + lane;
            float t  = R.tn + ((float)lane + 0.5f) * R.tstep;
            float px = fmaf(R.dx, t, R.ox);
            float py = fmaf(R.dy, t, R.oy);
            float pz = fmaf(R.dz, t, R.oz);
            float nx = fmaf(px - a0x, scx, -1.f);
            float ny = fmaf(py - a0y, scy, -1.f);
            float nz = fmaf(pz - a0z, scz, -1.f);
            bool ins = (nx >= -1.f) & (nx <= 1.f) & (ny >= -1.f) & (ny <= 1.f)
                     & (nz >= -1.f) & (nz <= 1.f);
            float sig = ins ? __expf(sm.a.SIG[m] + bdr) : 0.f;
            float delta = (lane == 63) ? (R.tf + 1.0f - t) : R.tstep;
            float tau = sig * delta * R.dnorm;
            float cum = tau;
            #pragma unroll
            for (int off = 1; off < 64; off <<= 1) {
                float tmp = __shfl_up(cum, off);
                if (lane >= off) cum += tmp;
            }
            float excl = cum - tau;
            float wgt = __expf(-excl) * (1.f - __expf(-tau));
            float c0 = wgt * sm.a.COL[m*4+0];
            float c1 = wgt * sm.a.COL[m*4+1];
            float c2 = wgt * sm.a.COL[m*4+2];
            float amv = wgt;
            float dmv = wgt * t;
            #pragma unroll
            for (int off = 32; off; off >>= 1) {
                c0  += __shfl_xor(c0,  off);
                c1  += __shfl_xor(c1,  off);
                c2  += __shfl_xor(c2,  off);
                amv += __shfl_xor(amv, off);
                dmv += __shfl_xor(dmv, off);
            }
            if (lane == 0) {
                float msk = R.act ? 1.f : 0.f;
                int ray = 2*gp + wv;
                out[ray*5+0] = c0*msk;
                out[ray*5+1] = c1*msk;
                out[ray*5+2] = c2*msk;
                out[ray*5+3] = amv*msk;
                out[ray*5+4] = dmv*msk;
            }
        }
        __syncthreads();

        // ========== L1 (MFMA): H1 = relu(W1ext^T · XYZ^T), bias via k=3 const-1 ==========
        {
            short8 bx[4];
            #pragma unroll
            for (int im = 0; im < 4; ++im)
                bx[im] = *(const short8*)&sm.a.CC[sw32(smB + 16*im + l15, 8*l4)];
            #pragma unroll
            for (int jn = 0; jn < 4; ++jn)
                #pragma unroll
                for (int im = 0; im < 4; ++im) {
                    f32x4 v = MFMA16(w1f[jn], bx[im], (f32x4){0.f,0.f,0.f,0.f});
                    int m  = smB + 16*im + l15;
                    int n0 = chB + 16*jn + 4*l4;
                    float r0 = fmaxf(v[0], 0.f), r1 = fmaxf(v[1], 0.f);
                    float r2 = fmaxf(v[2], 0.f), r3 = fmaxf(v[3], 0.f);
                    *(uint2*)&sm.a.H1[sw128(m, n0)] = make_uint2(pk2(r0,r1), pk2(r2,r3));
                }
        }
        __syncthreads();

        // ========== L2': H2 = relu(W2^T · H1^T + b2) ==========
        {
            f32x4 acc[4][4];
            #pragma unroll
            for (int jn = 0; jn < 4; ++jn)
                #pragma unroll
                for (int im = 0; im < 4; ++im) acc[jn][im] = (f32x4){0.f,0.f,0.f,0.f};
            #pragma unroll
            for (int kk = 0; kk < 4; ++kk) {
                short8 bfr[4];
                #pragma unroll
                for (int im = 0; im < 4; ++im)
                    bfr[im] = *(const short8*)&sm.a.H1[sw128(smB + 16*im + l15, kk*32 + 8*l4)];
                #pragma unroll
                for (int jn = 0; jn < 4; ++jn)
                    #pragma unroll
                    for (int im = 0; im < 4; ++im)
                        acc[jn][im] = MFMA16(w2f[jn][kk], bfr[im], acc[jn][im]);
            }
            #pragma unroll
            for (int jn = 0; jn < 4; ++jn)
                #pragma unroll
                for (int im = 0; im < 4; ++im) {
                    int m  = smB + 16*im + l15;
                    int n0 = chB + 16*jn + 4*l4;
                    f32x4 v = acc[jn][im];
                    float r0 = fmaxf(v[0] + b2r[jn][0], 0.f);
                    float r1 = fmaxf(v[1] + b2r[jn][1], 0.f);
                    float r2 = fmaxf(v[2] + b2r[jn][2], 0.f);
                    float r3 = fmaxf(v[3] + b2r[jn][3], 0.f);
                    *(uint2*)&sm.a.H2[sw128(m, n0)] = make_uint2(pk2(r0,r1), pk2(r2,r3));
                }
        }
        __syncthreads();

        // ========== G3': feat(+bf) -> CC[:,0:16], sigma-dot -> SIG ==========
        {
            f32x4 f3[2][2];
            #pragma unroll
            for (int cg = 0; cg < 2; ++cg) { f3[cg][0] = (f32x4){0,0,0,0}; f3[cg][1] = (f32x4){0,0,0,0}; }
            #pragma unroll
            for (int kk = 0; kk < 4; ++kk) {
                short8 bA = *(const short8*)&sm.a.H2[sw128(sB3 +      l15, kk*32 + 8*l4)];
                short8 bB = *(const short8*)&sm.a.H2[sw128(sB3 + 16 + l15, kk*32 + 8*l4)];
                #pragma unroll
                for (int cg = 0; cg < 2; ++cg) {
                    f3[cg][0] = MFMA16(wfdf[cg][kk], bA, f3[cg][0]);
                    f3[cg][1] = MFMA16(wfdf[cg][kk], bB, f3[cg][1]);
                }
            }
            #pragma unroll
            for (int sg = 0; sg < 2; ++sg) {
                int m = sB3 + 16*sg + l15;
                f32x4 v = f3[0][sg];
                *(uint2*)&sm.a.CC[sw32(m, 4*l4)] =
                    make_uint2(pk2(v[0]+bfr4[0], v[1]+bfr4[1]), pk2(v[2]+bfr4[2], v[3]+bfr4[3]));
                if (l4 == 0) sm.a.SIG[m] = f3[1][sg][0];
            }
        }
        __syncthreads();

        // ========== G4': HC = relu(Wc1^T · CC^T + bc1) -> H1 ==========
        {
            short8 bcc[4];
            #pragma unroll
            for (int sg = 0; sg < 4; ++sg)
                bcc[sg] = *(const short8*)&sm.a.CC[sw32(smB + 16*sg + l15, 8*l4)];
            #pragma unroll
            for (int cg = 0; cg < 4; ++cg)
                #pragma unroll
                for (int sg = 0; sg < 4; ++sg) {
                    f32x4 v = MFMA16(wc1f[cg], bcc[sg], (f32x4){0.f,0.f,0.f,0.f});
                    int m  = smB + 16*sg + l15;
                    int n0 = chB + 16*cg + 4*l4;
                    float r0 = fmaxf(v[0] + bc1r[cg][0], 0.f);
                    float r1 = fmaxf(v[1] + bc1r[cg][1], 0.f);
                    float r2 = fmaxf(v[2] + bc1r[cg][2], 0.f);
                    float r3 = fmaxf(v[3] + bc1r[cg][3], 0.f);
                    *(uint2*)&sm.a.H1[sw128(m, n0)] = make_uint2(pk2(r0,r1), pk2(r2,r3));
                }
        }
        __syncthreads();

        // ========== G5': color = sigmoid(Wc2^T · HC^T + bc2) -> COL ==========
        {
            f32x4 c5[2] = { (f32x4){0,0,0,0}, (f32x4){0,0,0,0} };
            #pragma unroll
            for (int kk = 0; kk < 4; ++kk) {
                #pragma unroll
                for (int sg = 0; sg < 2; ++sg) {
                    short8 b = *(const short8*)&sm.a.H1[sw128(sB3 + 16*sg + l15, kk*32 + 8*l4)];
                    c5[sg] = MFMA16(wc2f[kk], b, c5[sg]);
                }
            }
            if (l4 == 0) {
                #pragma unroll
                for (int sg = 0; sg < 2; ++sg) {
                    int m = sB3 + 16*sg + l15;
                    #pragma unroll
                    for (int vv = 0; vv < 3; ++vv)
                        sm.a.COL[m*4 + vv] = 1.f / (1.f + __expf(-(c5[sg][vv] + bc2r[vv])));
                }
            }
        }
        __syncthreads();

        // prep next-iteration F (waves 0,1 own rays 2g / 2g+1)
        if (wv < 2) Rp = raySetup(rays_o, rays_d, 2*g + wv, a0x,a0y,a0z,a1x,a1y,a1z);
        gp = g;
    }

    // trailing F for the last iteration
    if (gp >= 0 && wv < 2) {
        const RayP R = Rp;
        const int m = wv*64 + lane;
        float t  = R.tn + ((float)lane + 0.5f) * R.tstep;
        float px = fmaf(R.dx, t, R.ox);
        float py = fmaf(R.dy, t, R.oy);
        float pz = fmaf(R.dz, t, R.oz);
        float nx = fmaf(px - a0x, scx, -1.f);
        float ny = fmaf(py - a0y, scy, -1.f);
        float nz = fmaf(pz - a0z, scz, -1.f);
        bool ins = (nx >= -1.f) & (nx <= 1.f) & (ny >= -1.f) & (ny <= 1.f)
                 & (nz >= -1.f) & (nz <= 1.f);
        float sig = ins ? __expf(sm.a.SIG[m] + bdr) : 0.f;
        float delta = (lane == 63) ? (R.tf + 1.0f - t) : R.tstep;
        float tau = sig * delta * R.dnorm;
        float cum = tau;
        #pragma unroll
        for (int off = 1; off < 64; off <<= 1) {
            float tmp = __shfl_up(cum, off);
            if (lane >= off) cum += tmp;
        }
        float excl = cum - tau;
        float wgt = __expf(-excl) * (1.f - __expf(-tau));
        float c0 = wgt * sm.a.COL[m*4+0];
        float c1 = wgt * sm.a.COL[m*4+1];
        float c2 = wgt * sm.a.COL[m*4+2];
        float amv = wgt;
        float dmv = wgt * t;
        #pragma unroll
        for (int off = 32; off; off >>= 1) {
            c0  += __shfl_xor(c0,  off);
            c1  += __shfl_xor(c1,  off);
            c2  += __shfl_xor(c2,  off);
            amv += __shfl_xor(amv, off);
            dmv += __shfl_xor(dmv, off);
        }
        if (lane == 0) {
            float msk = R.act ? 1.f : 0.f;
            int ray = 2*gp + wv;
            out[ray*5+0] = c0*msk;
            out[ray*5+1] = c1*msk;
            out[ray*5+2] = c2*msk;
            out[ray*5+3] = amv*msk;
            out[ray*5+4] = dmv*msk;
        }
    }
}

extern "C" void kernel_launch(void* const* d_in, const int* in_sizes, int n_in,
                              void* d_out, int out_size, void* d_ws, size_t ws_size,
                              hipStream_t stream) {
    (void)in_sizes; (void)n_in; (void)d_ws; (void)ws_size; (void)out_size;
    const float* rays_o = (const float*)d_in[0];
    const float* rays_d = (const float*)d_in[1];
    const float* aabb   = (const float*)d_in[2];
    const float* W1  = (const float*)d_in[3];
    const float* b1  = (const float*)d_in[4];
    const float* W2  = (const float*)d_in[5];
    const float* b2  = (const float*)d_in[6];
    const float* Wd  = (const float*)d_in[7];
    const float* bd  = (const float*)d_in[8];
    const float* Wf  = (const float*)d_in[9];
    const float* bf  = (const float*)d_in[10];
    const float* Wc1 = (const float*)d_in[11];
    const float* bc1 = (const float*)d_in[12];
    const float* Wc2 = (const float*)d_in[13];
    const float* bc2 = (const float*)d_in[14];
    float* out = (float*)d_out;

    hipLaunchKernelGGL(RadianceRenderer_kernel, dim3(GRID), dim3(THREADS), 0, stream,
                       rays_o, rays_d, aabb, W1, b1, W2, b2, Wd, bd,
                       Wf, bf, Wc1, bc1, Wc2, bc2, out);
}

// Round 5
// 178.452 us; speedup vs baseline: 1.1146x; 1.1146x over previous
//
#include <hip/hip_runtime.h>
#include <math.h>

#define THREADS 256
#define GRID 512
#define NRAYS 8192
#define FAR_T 10.0f

typedef __attribute__((ext_vector_type(8))) short short8;
typedef __attribute__((ext_vector_type(4))) float f32x4;

static __device__ __forceinline__ unsigned f2bfu(float f) {
    unsigned u = __builtin_bit_cast(unsigned, f);
    return (u + 0x7fffu + ((u >> 16) & 1u)) >> 16;
}
// fast bf16x2 pack: round-half-up + v_perm_b32 byte select (3 VALU ops)
static __device__ __forceinline__ unsigned pk2(float a, float b) {
    unsigned ra = __builtin_bit_cast(unsigned, a) + 0x8000u;
    unsigned rb = __builtin_bit_cast(unsigned, b) + 0x8000u;
    return __builtin_amdgcn_perm(rb, ra, 0x07060302u);
}
static __device__ __forceinline__ int sw128(int r, int k) { return (r << 7) + (k ^ ((r & 7) << 3)); }
static __device__ __forceinline__ int sw32(int r, int k)  { return (r << 5) + (k ^ ((r & 3) << 3)); }
static __device__ __forceinline__ f32x4 MFMA16(short8 a, short8 b, f32x4 c) {
    return __builtin_amdgcn_mfma_f32_16x16x32_bf16(a, b, c, 0, 0, 0);
}

struct RayP { float ox,oy,oz,dx,dy,dz,tn,tf,tstep,dnorm; bool act; };

static __device__ __forceinline__ RayP raySetup(const float* __restrict__ ro, const float* __restrict__ rd,
        int r, float a0x,float a0y,float a0z,float a1x,float a1y,float a1z) {
    RayP R;
    R.ox=ro[3*r+0]; R.oy=ro[3*r+1]; R.oz=ro[3*r+2];
    R.dx=rd[3*r+0]; R.dy=rd[3*r+1]; R.dz=rd[3*r+2];
    float ivx=1.f/R.dx, ivy=1.f/R.dy, ivz=1.f/R.dz;
    float t1x=(a0x-R.ox)*ivx, t2x=(a1x-R.ox)*ivx;
    float t1y=(a0y-R.oy)*ivy, t2y=(a1y-R.oy)*ivy;
    float t1z=(a0z-R.oz)*ivz, t2z=(a1z-R.oz)*ivz;
    float tn = fmaxf(fmaxf(fminf(t1x,t2x),fminf(t1y,t2y)),fminf(t1z,t2z));
    tn = fmaxf(tn, 0.f);
    float tf = fminf(fminf(fmaxf(t1x,t2x),fmaxf(t1y,t2y)),fmaxf(t1z,t2z));
    tf = fminf(tf, FAR_T);
    R.act = tn < tf;
    R.tn = R.act ? tn : 0.f;
    R.tf = R.act ? tf : 1.f;
    R.tstep = (R.tf - R.tn) * (1.f/64.f);
    R.dnorm = sqrtf(R.dx*R.dx + R.dy*R.dy + R.dz*R.dz);
    return R;
}

__global__ __launch_bounds__(THREADS) __attribute__((amdgpu_waves_per_eu(2)))
void RadianceRenderer_kernel(const float* __restrict__ rays_o, const float* __restrict__ rays_d,
                             const float* __restrict__ aabb,
                             const float* __restrict__ W1, const float* __restrict__ b1,
                             const float* __restrict__ W2, const float* __restrict__ b2,
                             const float* __restrict__ Wd, const float* __restrict__ bd,
                             const float* __restrict__ Wf, const float* __restrict__ bf,
                             const float* __restrict__ Wc1, const float* __restrict__ bc1,
                             const float* __restrict__ Wc2, const float* __restrict__ bc2,
                             float* __restrict__ out)
{
    // persistent small weights (7.1 KB) — read per-iteration via predicated ds_read
    __shared__ short W1T[128*8];      // [ch][k0..7]: k<3 = W1, k==3 = b1, k>=4 = 0
    __shared__ short Wfd17[17*128];   // sw128: rows 0-15 = Wf cols, row 16 = Wd
    __shared__ short Wc2T3[3*128];    // linear: row c (<3) = Wc2 col c
    // big weights staged once into regs; staging region aliases activations (71.3 KB)
    __shared__ union {
        struct { short W2T[128*128]; short Wc1T[128*32]; } w;                    // 40 KB
        struct { short H1[128*128]; short H2[128*128]; short CC[128*16];
                 short YNM[2*16]; float SIG[128]; float COL[128*4]; } a;         // 71.3 KB
    } sm;

    const int tid  = threadIdx.x;
    const int lane = tid & 63;
    const int wv   = tid >> 6;
    const int l15  = lane & 15;
    const int l4   = lane >> 4;
    const short8 z8 = {0,0,0,0,0,0,0,0};

    // ---- stage weights ----
    for (int i = tid; i < 128*128; i += THREADS) {
        int k = i >> 7, n = i & 127;
        sm.w.W2T[sw128(n, k)] = (short)f2bfu(W2[i]);
    }
    for (int i = tid; i < 128*32; i += THREADS) {
        int n = i >> 5, k = i & 31;
        sm.w.Wc1T[sw32(n, k)] = (short)f2bfu(Wc1[k*128 + n]);
    }
    for (int i = tid; i < 17*128; i += THREADS) {
        int n = i >> 7, k = i & 127;
        float v = (n < 16) ? Wf[k*16 + n] : Wd[k];
        Wfd17[sw128(n, k)] = (short)f2bfu(v);
    }
    for (int i = tid; i < 3*128; i += THREADS) {
        int c = i >> 7, k = i & 127;
        Wc2T3[i] = (short)f2bfu(Wc2[k*3 + c]);
    }
    for (int i = tid; i < 128*8; i += THREADS) {
        int ch = i >> 3, k = i & 7;
        float f = (k < 3) ? W1[k*128 + ch] : ((k == 3) ? b1[ch] : 0.f);
        W1T[i] = (short)f2bfu(f);
    }
    __syncthreads();

    const int chB = (wv >> 1) * 64;
    const int smB = (wv & 1) * 64;
    const int sB3 = wv * 32;

    // register-resident: only the two big weight matrices
    short8 w2f[4][4], wc1f[4];
    #pragma unroll
    for (int jn = 0; jn < 4; ++jn)
        #pragma unroll
        for (int kk = 0; kk < 4; ++kk)
            w2f[jn][kk] = *(const short8*)&sm.w.W2T[sw128(chB + 16*jn + l15, kk*32 + 8*l4)];
    #pragma unroll
    for (int cg = 0; cg < 4; ++cg)
        wc1f[cg] = *(const short8*)&sm.w.Wc1T[sw32(chB + 16*cg + l15, 8*l4)];

    float b2r[4][4], bc1r[4][4];
    #pragma unroll
    for (int jn = 0; jn < 4; ++jn)
        #pragma unroll
        for (int vv = 0; vv < 4; ++vv) {
            b2r[jn][vv]  = b2[chB + 16*jn + 4*l4 + vv];
            bc1r[jn][vv] = bc1[chB + 16*jn + 4*l4 + vv];
        }
    f32x4 bfv;
    #pragma unroll
    for (int vv = 0; vv < 4; ++vv) bfv[vv] = bf[4*l4 + vv];
    float bc2r[3] = { bc2[0], bc2[1], bc2[2] };
    const float bdr = bd[0];

    const float a0x=aabb[0],a0y=aabb[1],a0z=aabb[2],a1x=aabb[3],a1y=aabb[4],a1z=aabb[5];
    const float scx=2.f/(a1x-a0x), scy=2.f/(a1y-a0y), scz=2.f/(a1z-a0z);

    __syncthreads();   // staging reads done before Act writes

    // zero CC once: first L1 reads CC cols 4..7 before G3' ever writes them
    for (int i = tid; i < 1024; i += THREADS) ((unsigned*)sm.a.CC)[i] = 0u;
    __syncthreads();

    int gp = -1;
    RayP Rp;

    for (int g = blockIdx.x; g < NRAYS/2; g += gridDim.x) {
        // ========== A0 (waves 2,3): xyz rows + per-ray ynm  ||  F(gp) (waves 0,1) ==========
        if (wv >= 2) {
            const int m   = tid - 128;          // sample row 0..127
            const int ray = 2*g + (m >> 6);
            RayP R = raySetup(rays_o, rays_d, ray, a0x,a0y,a0z,a1x,a1y,a1z);
            const int s = m & 63;
            float t  = R.tn + ((float)s + 0.5f) * R.tstep;
            float px = fmaf(R.dx, t, R.ox);
            float py = fmaf(R.dy, t, R.oy);
            float pz = fmaf(R.dz, t, R.oz);
            float nx = fmaf(px - a0x, scx, -1.f);
            float ny = fmaf(py - a0y, scy, -1.f);
            float nz = fmaf(pz - a0z, scz, -1.f);
            *(uint2*)&sm.a.CC[m*16] = make_uint2(pk2(nx, ny), pk2(nz, 1.0f));
            if (s == 0) {   // one thread per ray writes ynm (16 bf16)
                float inorm = 1.f / R.dnorm;
                float x = R.dx*inorm, y = R.dy*inorm, z = R.dz*inorm;
                float x2 = x*x, y2 = y*y, z2 = z*z;
                unsigned q0 = pk2(0.282094791773878f,              -0.488602511902920f*y);
                unsigned q1 = pk2(0.488602511902920f*z,            -0.488602511902920f*x);
                unsigned q2 = pk2(1.092548430592079f*x*y,          -1.092548430592079f*y*z);
                unsigned q3 = pk2(0.315391565252520f*(3.f*z2-1.f), -1.092548430592079f*x*z);
                unsigned q4 = pk2(0.546274215296040f*(x2-y2),      -0.590043589926644f*y*(3.f*x2-y2));
                unsigned q5 = pk2(2.890611442640554f*x*y*z,        -0.457045799464466f*y*(5.f*z2-1.f));
                unsigned q6 = pk2(0.373176332590115f*z*(5.f*z2-3.f), -0.457045799464466f*x*(5.f*z2-1.f));
                unsigned q7 = pk2(1.445305721320277f*z*(x2-y2),    -0.590043589926644f*x*(x2-3.f*y2));
                *(uint4*)&sm.a.YNM[(m >> 6)*16    ] = make_uint4(q0,q1,q2,q3);
                *(uint4*)&sm.a.YNM[(m >> 6)*16 + 8] = make_uint4(q4,q5,q6,q7);
            }
        } else if (gp >= 0) {
            // ========== F: transmittance integration for previous iteration ==========
            const RayP R = Rp;
            const int m = wv*64 + lane;
            float t  = R.tn + ((float)lane + 0.5f) * R.tstep;
            float px = fmaf(R.dx, t, R.ox);
            float py = fmaf(R.dy, t, R.oy);
            float pz = fmaf(R.dz, t, R.oz);
            float nx = fmaf(px - a0x, scx, -1.f);
            float ny = fmaf(py - a0y, scy, -1.f);
            float nz = fmaf(pz - a0z, scz, -1.f);
            bool ins = (nx >= -1.f) & (nx <= 1.f) & (ny >= -1.f) & (ny <= 1.f)
                     & (nz >= -1.f) & (nz <= 1.f);
            float sig = ins ? __expf(sm.a.SIG[m] + bdr) : 0.f;
            float delta = (lane == 63) ? (R.tf + 1.0f - t) : R.tstep;
            float tau = sig * delta * R.dnorm;
            float cum = tau;
            #pragma unroll
            for (int off = 1; off < 64; off <<= 1) {
                float tmp = __shfl_up(cum, off);
                if (lane >= off) cum += tmp;
            }
            float excl = cum - tau;
            float wgt = __expf(-excl) * (1.f - __expf(-tau));
            float c0 = wgt * sm.a.COL[m*4+0];
            float c1 = wgt * sm.a.COL[m*4+1];
            float c2 = wgt * sm.a.COL[m*4+2];
            float amv = wgt;
            float dmv = wgt * t;
            #pragma unroll
            for (int off = 32; off; off >>= 1) {
                c0  += __shfl_xor(c0,  off);
                c1  += __shfl_xor(c1,  off);
                c2  += __shfl_xor(c2,  off);
                amv += __shfl_xor(amv, off);
                dmv += __shfl_xor(dmv, off);
            }
            if (lane == 0) {
                float msk = R.act ? 1.f : 0.f;
                int ray = 2*gp + wv;
                out[ray*5+0] = c0*msk;
                out[ray*5+1] = c1*msk;
                out[ray*5+2] = c2*msk;
                out[ray*5+3] = amv*msk;
                out[ray*5+4] = dmv*msk;
            }
        }
        __syncthreads();

        // ========== L1 (MFMA): H1 = relu(W1ext^T · XYZ^T), bias via k=3 const-1 ==========
        {
            short8 bx[4];
            #pragma unroll
            for (int im = 0; im < 4; ++im) {
                short8 v = z8;
                if (l4 == 0) v = *(const short8*)&sm.a.CC[(smB + 16*im + l15)*16];
                bx[im] = v;
            }
            #pragma unroll
            for (int jn = 0; jn < 4; ++jn) {
                short8 w1fr = z8;
                if (l4 == 0) w1fr = *(const short8*)&W1T[(chB + 16*jn + l15)*8];
                #pragma unroll
                for (int im = 0; im < 4; ++im) {
                    f32x4 v = MFMA16(w1fr, bx[im], (f32x4){0.f,0.f,0.f,0.f});
                    int m  = smB + 16*im + l15;
                    int n0 = chB + 16*jn + 4*l4;
                    float r0 = fmaxf(v[0], 0.f), r1 = fmaxf(v[1], 0.f);
                    float r2 = fmaxf(v[2], 0.f), r3 = fmaxf(v[3], 0.f);
                    *(uint2*)&sm.a.H1[sw128(m, n0)] = make_uint2(pk2(r0,r1), pk2(r2,r3));
                }
            }
        }
        __syncthreads();

        // ========== L2': H2 = relu(W2^T · H1^T + b2) — acc init with bias ==========
        {
            f32x4 acc[4][4];
            #pragma unroll
            for (int jn = 0; jn < 4; ++jn)
                #pragma unroll
                for (int im = 0; im < 4; ++im)
                    acc[jn][im] = (f32x4){b2r[jn][0], b2r[jn][1], b2r[jn][2], b2r[jn][3]};
            #pragma unroll
            for (int kk = 0; kk < 4; ++kk) {
                short8 bfr[4];
                #pragma unroll
                for (int im = 0; im < 4; ++im)
                    bfr[im] = *(const short8*)&sm.a.H1[sw128(smB + 16*im + l15, kk*32 + 8*l4)];
                #pragma unroll
                for (int jn = 0; jn < 4; ++jn)
                    #pragma unroll
                    for (int im = 0; im < 4; ++im)
                        acc[jn][im] = MFMA16(w2f[jn][kk], bfr[im], acc[jn][im]);
            }
            #pragma unroll
            for (int jn = 0; jn < 4; ++jn)
                #pragma unroll
                for (int im = 0; im < 4; ++im) {
                    int m  = smB + 16*im + l15;
                    int n0 = chB + 16*jn + 4*l4;
                    f32x4 v = acc[jn][im];
                    float r0 = fmaxf(v[0], 0.f), r1 = fmaxf(v[1], 0.f);
                    float r2 = fmaxf(v[2], 0.f), r3 = fmaxf(v[3], 0.f);
                    *(uint2*)&sm.a.H2[sw128(m, n0)] = make_uint2(pk2(r0,r1), pk2(r2,r3));
                }
        }
        __syncthreads();

        // ========== G3': feat(+bf) -> CC[:,0:16], sigma-dot -> SIG ==========
        {
            f32x4 f30[2] = { bfv, bfv };                              // feat acc (bias-init)
            f32x4 f31[2] = { (f32x4){0,0,0,0}, (f32x4){0,0,0,0} };    // sigma acc
            #pragma unroll
            for (int kk = 0; kk < 4; ++kk) {
                short8 bA = *(const short8*)&sm.a.H2[sw128(sB3 +      l15, kk*32 + 8*l4)];
                short8 bB = *(const short8*)&sm.a.H2[sw128(sB3 + 16 + l15, kk*32 + 8*l4)];
                short8 wfd0 = *(const short8*)&Wfd17[sw128(l15, kk*32 + 8*l4)];
                short8 wfd1 = z8;
                if (l15 == 0) wfd1 = *(const short8*)&Wfd17[sw128(16, kk*32 + 8*l4)];
                f30[0] = MFMA16(wfd0, bA, f30[0]);
                f30[1] = MFMA16(wfd0, bB, f30[1]);
                f31[0] = MFMA16(wfd1, bA, f31[0]);
                f31[1] = MFMA16(wfd1, bB, f31[1]);
            }
            #pragma unroll
            for (int sg = 0; sg < 2; ++sg) {
                int m = sB3 + 16*sg + l15;
                f32x4 v = f30[sg];
                *(uint2*)&sm.a.CC[m*16 + 4*l4] = make_uint2(pk2(v[0],v[1]), pk2(v[2],v[3]));
                if (l4 == 0) sm.a.SIG[m] = f31[sg][0];
            }
        }
        __syncthreads();

        // ========== G4': HC = relu(Wc1^T · [feat|ynm]^T + bc1) -> H1 ==========
        {
            short8 bcc[4];
            #pragma unroll
            for (int sg = 0; sg < 4; ++sg) {
                int m = smB + 16*sg + l15;
                if (l4 < 2) bcc[sg] = *(const short8*)&sm.a.CC[m*16 + 8*l4];
                else        bcc[sg] = *(const short8*)&sm.a.YNM[(m >> 6)*16 + 8*(l4 - 2)];
            }
            #pragma unroll
            for (int cg = 0; cg < 4; ++cg)
                #pragma unroll
                for (int sg = 0; sg < 4; ++sg) {
                    f32x4 v = MFMA16(wc1f[cg], bcc[sg],
                                     (f32x4){bc1r[cg][0], bc1r[cg][1], bc1r[cg][2], bc1r[cg][3]});
                    int m  = smB + 16*sg + l15;
                    int n0 = chB + 16*cg + 4*l4;
                    float r0 = fmaxf(v[0], 0.f), r1 = fmaxf(v[1], 0.f);
                    float r2 = fmaxf(v[2], 0.f), r3 = fmaxf(v[3], 0.f);
                    *(uint2*)&sm.a.H1[sw128(m, n0)] = make_uint2(pk2(r0,r1), pk2(r2,r3));
                }
        }
        __syncthreads();

        // ========== G5': color = sigmoid(Wc2^T · HC^T + bc2) -> COL ==========
        {
            f32x4 c5[2] = { (f32x4){0,0,0,0}, (f32x4){0,0,0,0} };
            #pragma unroll
            for (int kk = 0; kk < 4; ++kk) {
                short8 wc2fr = z8;
                if (l15 < 3) wc2fr = *(const short8*)&Wc2T3[l15*128 + kk*32 + 8*l4];
                #pragma unroll
                for (int sg = 0; sg < 2; ++sg) {
                    short8 b = *(const short8*)&sm.a.H1[sw128(sB3 + 16*sg + l15, kk*32 + 8*l4)];
                    c5[sg] = MFMA16(wc2fr, b, c5[sg]);
                }
            }
            if (l4 == 0) {
                #pragma unroll
                for (int sg = 0; sg < 2; ++sg) {
                    int m = sB3 + 16*sg + l15;
                    #pragma unroll
                    for (int vv = 0; vv < 3; ++vv)
                        sm.a.COL[m*4 + vv] = 1.f / (1.f + __expf(-(c5[sg][vv] + bc2r[vv])));
                }
            }
        }
        __syncthreads();

        if (wv < 2) Rp = raySetup(rays_o, rays_d, 2*g + wv, a0x,a0y,a0z,a1x,a1y,a1z);
        gp = g;
    }

    // trailing F for the last iteration
    if (gp >= 0 && wv < 2) {
        const RayP R = Rp;
        const int m = wv*64 + lane;
        float t  = R.tn + ((float)lane + 0.5f) * R.tstep;
        float px = fmaf(R.dx, t, R.ox);
        float py = fmaf(R.dy, t, R.oy);
        float pz = fmaf(R.dz, t, R.oz);
        float nx = fmaf(px - a0x, scx, -1.f);
        float ny = fmaf(py - a0y, scy, -1.f);
        float nz = fmaf(pz - a0z, scz, -1.f);
        bool ins = (nx >= -1.f) & (nx <= 1.f) & (ny >= -1.f) & (ny <= 1.f)
                 & (nz >= -1.f) & (nz <= 1.f);
        float sig = ins ? __expf(sm.a.SIG[m] + bdr) : 0.f;
        float delta = (lane == 63) ? (R.tf + 1.0f - t) : R.tstep;
        float tau = sig * delta * R.dnorm;
        float cum = tau;
        #pragma unroll
        for (int off = 1; off < 64; off <<= 1) {
            float tmp = __shfl_up(cum, off);
            if (lane >= off) cum += tmp;
        }
        float excl = cum - tau;
        float wgt = __expf(-excl) * (1.f - __expf(-tau));
        float c0 = wgt * sm.a.COL[m*4+0];
        float c1 = wgt * sm.a.COL[m*4+1];
        float c2 = wgt * sm.a.COL[m*4+2];
        float amv = wgt;
        float dmv = wgt * t;
        #pragma unroll
        for (int off = 32; off; off >>= 1) {
            c0  += __shfl_xor(c0,  off);
            c1  += __shfl_xor(c1,  off);
            c2  += __shfl_xor(c2,  off);
            amv += __shfl_xor(amv, off);
            dmv += __shfl_xor(dmv, off);
        }
        if (lane == 0) {
            float msk = R.act ? 1.f : 0.f;
            int ray = 2*gp + wv;
            out[ray*5+0] = c0*msk;
            out[ray*5+1] = c1*msk;
            out[ray*5+2] = c2*msk;
            out[ray*5+3] = amv*msk;
            out[ray*5+4] = dmv*msk;
        }
    }
}

extern "C" void kernel_launch(void* const* d_in, const int* in_sizes, int n_in,
                              void* d_out, int out_size, void* d_ws, size_t ws_size,
                              hipStream_t stream) {
    (void)in_sizes; (void)n_in; (void)d_ws; (void)ws_size; (void)out_size;
    const float* rays_o = (const float*)d_in[0];
    const float* rays_d = (const float*)d_in[1];
    const float* aabb   = (const float*)d_in[2];
    const float* W1  = (const float*)d_in[3];
    const float* b1  = (const float*)d_in[4];
    const float* W2  = (const float*)d_in[5];
    const float* b2  = (const float*)d_in[6];
    const float* Wd  = (const float*)d_in[7];
    const float* bd  = (const float*)d_in[8];
    const float* Wf  = (const float*)d_in[9];
    const float* bf  = (const float*)d_in[10];
    const float* Wc1 = (const float*)d_in[11];
    const float* bc1 = (const float*)d_in[12];
    const float* Wc2 = (const float*)d_in[13];
    const float* bc2 = (const float*)d_in[14];
    float* out = (float*)d_out;

    hipLaunchKernelGGL(RadianceRenderer_kernel, dim3(GRID), dim3(THREADS), 0, stream,
                       rays_o, rays_d, aabb, W1, b1, W2, b2, Wd, bd,
                       Wf, bf, Wc1, bc1, Wc2, bc2, out);
}

// Round 7
// 177.927 us; speedup vs baseline: 1.1179x; 1.0029x over previous
//
#include <hip/hip_runtime.h>
#include <math.h>

#define THREADS 256
#define GRID 512
#define NRAYS 8192
#define FAR_T 10.0f

typedef __attribute__((ext_vector_type(8))) short short8;
typedef __attribute__((ext_vector_type(4))) float f32x4;

static __device__ __forceinline__ unsigned f2bfu(float f) {
    unsigned u = __builtin_bit_cast(unsigned, f);
    return (u + 0x7fffu + ((u >> 16) & 1u)) >> 16;
}
// fast bf16x2 pack: round-half-up + v_perm_b32 byte select (3 VALU ops)
static __device__ __forceinline__ unsigned pk2(float a, float b) {
    unsigned ra = __builtin_bit_cast(unsigned, a) + 0x8000u;
    unsigned rb = __builtin_bit_cast(unsigned, b) + 0x8000u;
    return __builtin_amdgcn_perm(rb, ra, 0x07060302u);
}
static __device__ __forceinline__ int sw128(int r, int k) { return (r << 7) + (k ^ ((r & 7) << 3)); }
static __device__ __forceinline__ int sw32(int r, int k)  { return (r << 5) + (k ^ ((r & 3) << 3)); }
static __device__ __forceinline__ f32x4 MFMA16(short8 a, short8 b, f32x4 c) {
    return __builtin_amdgcn_mfma_f32_16x16x32_bf16(a, b, c, 0, 0, 0);
}

struct RayP { float ox,oy,oz,dx,dy,dz,tn,tf,tstep,dnorm; bool act; };

static __device__ __forceinline__ RayP raySetup(const float* __restrict__ ro, const float* __restrict__ rd,
        int r, float a0x,float a0y,float a0z,float a1x,float a1y,float a1z) {
    RayP R;
    R.ox=ro[3*r+0]; R.oy=ro[3*r+1]; R.oz=ro[3*r+2];
    R.dx=rd[3*r+0]; R.dy=rd[3*r+1]; R.dz=rd[3*r+2];
    float ivx=1.f/R.dx, ivy=1.f/R.dy, ivz=1.f/R.dz;
    float t1x=(a0x-R.ox)*ivx, t2x=(a1x-R.ox)*ivx;
    float t1y=(a0y-R.oy)*ivy, t2y=(a1y-R.oy)*ivy;
    float t1z=(a0z-R.oz)*ivz, t2z=(a1z-R.oz)*ivz;
    float tn = fmaxf(fmaxf(fminf(t1x,t2x),fminf(t1y,t2y)),fminf(t1z,t2z));
    tn = fmaxf(tn, 0.f);
    float tf = fminf(fminf(fmaxf(t1x,t2x),fmaxf(t1y,t2y)),fmaxf(t1z,t2z));
    tf = fminf(tf, FAR_T);
    R.act = tn < tf;
    R.tn = R.act ? tn : 0.f;
    R.tf = R.act ? tf : 1.f;
    R.tstep = (R.tf - R.tn) * (1.f/64.f);
    R.dnorm = sqrtf(R.dx*R.dx + R.dy*R.dy + R.dz*R.dz);
    return R;
}

__global__ __launch_bounds__(THREADS) __attribute__((amdgpu_waves_per_eu(2, 2)))
void RadianceRenderer_kernel(const float* __restrict__ rays_o, const float* __restrict__ rays_d,
                             const float* __restrict__ aabb,
                             const float* __restrict__ W1, const float* __restrict__ b1,
                             const float* __restrict__ W2, const float* __restrict__ b2,
                             const float* __restrict__ Wd, const float* __restrict__ bd,
                             const float* __restrict__ Wf, const float* __restrict__ bf,
                             const float* __restrict__ Wc1, const float* __restrict__ bc1,
                             const float* __restrict__ Wc2, const float* __restrict__ bc2,
                             float* __restrict__ out)
{
    // persistent small weights (7.1 KB) — read per-iteration via predicated ds_read
    __shared__ short W1T[128*8];      // [ch][k0..7]: k<3 = W1, k==3 = b1, k>=4 = 0
    __shared__ short Wfd17[17*128];   // sw128: rows 0-15 = Wf cols, row 16 = Wd
    __shared__ short Wc2T3[3*128];    // linear: row c (<3) = Wc2 col c
    // big weights staged once into regs; staging region aliases activations (71.3 KB)
    __shared__ union {
        struct { short W2T[128*128]; short Wc1T[128*32]; } w;                    // 40 KB
        struct { short H1[128*128]; short H2[128*128]; short CC[128*16];
                 short YNM[2*16]; float SIG[128]; float COL[128*4]; } a;         // 71.3 KB
    } sm;

    const int tid  = threadIdx.x;
    const int lane = tid & 63;
    const int wv   = tid >> 6;
    const int l15  = lane & 15;
    const int l4   = lane >> 4;
    const short8 z8 = {0,0,0,0,0,0,0,0};

    // ---- stage weights ----
    for (int i = tid; i < 128*128; i += THREADS) {
        int k = i >> 7, n = i & 127;
        sm.w.W2T[sw128(n, k)] = (short)f2bfu(W2[i]);
    }
    for (int i = tid; i < 128*32; i += THREADS) {
        int n = i >> 5, k = i & 31;
        sm.w.Wc1T[sw32(n, k)] = (short)f2bfu(Wc1[k*128 + n]);
    }
    for (int i = tid; i < 17*128; i += THREADS) {
        int n = i >> 7, k = i & 127;
        float v = (n < 16) ? Wf[k*16 + n] : Wd[k];
        Wfd17[sw128(n, k)] = (short)f2bfu(v);
    }
    for (int i = tid; i < 3*128; i += THREADS) {
        int c = i >> 7, k = i & 127;
        Wc2T3[i] = (short)f2bfu(Wc2[k*3 + c]);
    }
    for (int i = tid; i < 128*8; i += THREADS) {
        int ch = i >> 3, k = i & 7;
        float f = (k < 3) ? W1[k*128 + ch] : ((k == 3) ? b1[ch] : 0.f);
        W1T[i] = (short)f2bfu(f);
    }
    __syncthreads();

    const int chB = (wv >> 1) * 64;
    const int smB = (wv & 1) * 64;
    const int sB3 = wv * 32;

    // register-resident: only the two big weight matrices
    short8 w2f[4][4], wc1f[4];
    #pragma unroll
    for (int jn = 0; jn < 4; ++jn)
        #pragma unroll
        for (int kk = 0; kk < 4; ++kk)
            w2f[jn][kk] = *(const short8*)&sm.w.W2T[sw128(chB + 16*jn + l15, kk*32 + 8*l4)];
    #pragma unroll
    for (int cg = 0; cg < 4; ++cg)
        wc1f[cg] = *(const short8*)&sm.w.Wc1T[sw32(chB + 16*cg + l15, 8*l4)];

    float b2r[4][4], bc1r[4][4];
    #pragma unroll
    for (int jn = 0; jn < 4; ++jn)
        #pragma unroll
        for (int vv = 0; vv < 4; ++vv) {
            b2r[jn][vv]  = b2[chB + 16*jn + 4*l4 + vv];
            bc1r[jn][vv] = bc1[chB + 16*jn + 4*l4 + vv];
        }
    f32x4 bfv;
    #pragma unroll
    for (int vv = 0; vv < 4; ++vv) bfv[vv] = bf[4*l4 + vv];
    float bc2r[3] = { bc2[0], bc2[1], bc2[2] };
    const float bdr = bd[0];

    const float a0x=aabb[0],a0y=aabb[1],a0z=aabb[2],a1x=aabb[3],a1y=aabb[4],a1z=aabb[5];
    const float scx=2.f/(a1x-a0x), scy=2.f/(a1y-a0y), scz=2.f/(a1z-a0z);

    __syncthreads();   // staging reads done before Act writes

    // zero CC once: first L1 reads CC cols 4..7 before G3' ever writes them
    for (int i = tid; i < 1024; i += THREADS) ((unsigned*)sm.a.CC)[i] = 0u;
    __syncthreads();

    int gp = -1;
    RayP Rp;

    for (int g = blockIdx.x; g < NRAYS/2; g += gridDim.x) {
        // ========== A0 (waves 2,3): xyz rows + per-ray ynm  ||  F(gp) (waves 0,1) ==========
        if (wv >= 2) {
            const int m   = tid - 128;          // sample row 0..127
            const int ray = 2*g + (m >> 6);
            RayP R = raySetup(rays_o, rays_d, ray, a0x,a0y,a0z,a1x,a1y,a1z);
            const int s = m & 63;
            float t  = R.tn + ((float)s + 0.5f) * R.tstep;
            float px = fmaf(R.dx, t, R.ox);
            float py = fmaf(R.dy, t, R.oy);
            float pz = fmaf(R.dz, t, R.oz);
            float nx = fmaf(px - a0x, scx, -1.f);
            float ny = fmaf(py - a0y, scy, -1.f);
            float nz = fmaf(pz - a0z, scz, -1.f);
            *(uint2*)&sm.a.CC[m*16] = make_uint2(pk2(nx, ny), pk2(nz, 1.0f));
            if (s == 0) {   // one thread per ray writes ynm (16 bf16)
                float inorm = 1.f / R.dnorm;
                float x = R.dx*inorm, y = R.dy*inorm, z = R.dz*inorm;
                float x2 = x*x, y2 = y*y, z2 = z*z;
                unsigned q0 = pk2(0.282094791773878f,              -0.488602511902920f*y);
                unsigned q1 = pk2(0.488602511902920f*z,            -0.488602511902920f*x);
                unsigned q2 = pk2(1.092548430592079f*x*y,          -1.092548430592079f*y*z);
                unsigned q3 = pk2(0.315391565252520f*(3.f*z2-1.f), -1.092548430592079f*x*z);
                unsigned q4 = pk2(0.546274215296040f*(x2-y2),      -0.590043589926644f*y*(3.f*x2-y2));
                unsigned q5 = pk2(2.890611442640554f*x*y*z,        -0.457045799464466f*y*(5.f*z2-1.f));
                unsigned q6 = pk2(0.373176332590115f*z*(5.f*z2-3.f), -0.457045799464466f*x*(5.f*z2-1.f));
                unsigned q7 = pk2(1.445305721320277f*z*(x2-y2),    -0.590043589926644f*x*(x2-3.f*y2));
                *(uint4*)&sm.a.YNM[(m >> 6)*16    ] = make_uint4(q0,q1,q2,q3);
                *(uint4*)&sm.a.YNM[(m >> 6)*16 + 8] = make_uint4(q4,q5,q6,q7);
            }
        } else if (gp >= 0) {
            // ========== F: transmittance integration for previous iteration ==========
            const RayP R = Rp;
            const int m = wv*64 + lane;
            float t  = R.tn + ((float)lane + 0.5f) * R.tstep;
            float px = fmaf(R.dx, t, R.ox);
            float py = fmaf(R.dy, t, R.oy);
            float pz = fmaf(R.dz, t, R.oz);
            float nx = fmaf(px - a0x, scx, -1.f);
            float ny = fmaf(py - a0y, scy, -1.f);
            float nz = fmaf(pz - a0z, scz, -1.f);
            bool ins = (nx >= -1.f) & (nx <= 1.f) & (ny >= -1.f) & (ny <= 1.f)
                     & (nz >= -1.f) & (nz <= 1.f);
            float sig = ins ? __expf(sm.a.SIG[m] + bdr) : 0.f;
            float delta = (lane == 63) ? (R.tf + 1.0f - t) : R.tstep;
            float tau = sig * delta * R.dnorm;
            float cum = tau;
            #pragma unroll
            for (int off = 1; off < 64; off <<= 1) {
                float tmp = __shfl_up(cum, off);
                if (lane >= off) cum += tmp;
            }
            float excl = cum - tau;
            float wgt = __expf(-excl) * (1.f - __expf(-tau));
            float c0 = wgt * sm.a.COL[m*4+0];
            float c1 = wgt * sm.a.COL[m*4+1];
            float c2 = wgt * sm.a.COL[m*4+2];
            float amv = wgt;
            float dmv = wgt * t;
            #pragma unroll
            for (int off = 32; off; off >>= 1) {
                c0  += __shfl_xor(c0,  off);
                c1  += __shfl_xor(c1,  off);
                c2  += __shfl_xor(c2,  off);
                amv += __shfl_xor(amv, off);
                dmv += __shfl_xor(dmv, off);
            }
            if (lane == 0) {
                float msk = R.act ? 1.f : 0.f;
                int ray = 2*gp + wv;
                out[ray*5+0] = c0*msk;
                out[ray*5+1] = c1*msk;
                out[ray*5+2] = c2*msk;
                out[ray*5+3] = amv*msk;
                out[ray*5+4] = dmv*msk;
            }
        }
        __syncthreads();

        // ========== L1 (MFMA): H1 = relu(W1ext^T · XYZ^T), bias via k=3 const-1 ==========
        {
            short8 bx[4];
            #pragma unroll
            for (int im = 0; im < 4; ++im) {
                short8 v = z8;
                if (l4 == 0) v = *(const short8*)&sm.a.CC[(smB + 16*im + l15)*16];
                bx[im] = v;
            }
            #pragma unroll
            for (int jn = 0; jn < 4; ++jn) {
                short8 w1fr = z8;
                if (l4 == 0) w1fr = *(const short8*)&W1T[(chB + 16*jn + l15)*8];
                #pragma unroll
                for (int im = 0; im < 4; ++im) {
                    f32x4 v = MFMA16(w1fr, bx[im], (f32x4){0.f,0.f,0.f,0.f});
                    int m  = smB + 16*im + l15;
                    int n0 = chB + 16*jn + 4*l4;
                    float r0 = fmaxf(v[0], 0.f), r1 = fmaxf(v[1], 0.f);
                    float r2 = fmaxf(v[2], 0.f), r3 = fmaxf(v[3], 0.f);
                    *(uint2*)&sm.a.H1[sw128(m, n0)] = make_uint2(pk2(r0,r1), pk2(r2,r3));
                }
            }
        }
        __syncthreads();

        // ========== L2': H2 = relu(W2^T · H1^T + b2) — acc init with bias ==========
        {
            f32x4 acc[4][4];
            #pragma unroll
            for (int jn = 0; jn < 4; ++jn)
                #pragma unroll
                for (int im = 0; im < 4; ++im)
                    acc[jn][im] = (f32x4){b2r[jn][0], b2r[jn][1], b2r[jn][2], b2r[jn][3]};
            #pragma unroll
            for (int kk = 0; kk < 4; ++kk) {
                short8 bfr[4];
                #pragma unroll
                for (int im = 0; im < 4; ++im)
                    bfr[im] = *(const short8*)&sm.a.H1[sw128(smB + 16*im + l15, kk*32 + 8*l4)];
                #pragma unroll
                for (int jn = 0; jn < 4; ++jn)
                    #pragma unroll
                    for (int im = 0; im < 4; ++im)
                        acc[jn][im] = MFMA16(w2f[jn][kk], bfr[im], acc[jn][im]);
            }
            #pragma unroll
            for (int jn = 0; jn < 4; ++jn)
                #pragma unroll
                for (int im = 0; im < 4; ++im) {
                    int m  = smB + 16*im + l15;
                    int n0 = chB + 16*jn + 4*l4;
                    f32x4 v = acc[jn][im];
                    float r0 = fmaxf(v[0], 0.f), r1 = fmaxf(v[1], 0.f);
                    float r2 = fmaxf(v[2], 0.f), r3 = fmaxf(v[3], 0.f);
                    *(uint2*)&sm.a.H2[sw128(m, n0)] = make_uint2(pk2(r0,r1), pk2(r2,r3));
                }
        }
        __syncthreads();

        // ========== G3': feat(+bf) -> CC[:,0:16], sigma-dot -> SIG ==========
        {
            f32x4 f30[2] = { bfv, bfv };                              // feat acc (bias-init)
            f32x4 f31[2] = { (f32x4){0,0,0,0}, (f32x4){0,0,0,0} };    // sigma acc
            #pragma unroll
            for (int kk = 0; kk < 4; ++kk) {
                short8 bA = *(const short8*)&sm.a.H2[sw128(sB3 +      l15, kk*32 + 8*l4)];
                short8 bB = *(const short8*)&sm.a.H2[sw128(sB3 + 16 + l15, kk*32 + 8*l4)];
                short8 wfd0 = *(const short8*)&Wfd17[sw128(l15, kk*32 + 8*l4)];
                short8 wfd1 = z8;
                if (l15 == 0) wfd1 = *(const short8*)&Wfd17[sw128(16, kk*32 + 8*l4)];
                f30[0] = MFMA16(wfd0, bA, f30[0]);
                f30[1] = MFMA16(wfd0, bB, f30[1]);
                f31[0] = MFMA16(wfd1, bA, f31[0]);
                f31[1] = MFMA16(wfd1, bB, f31[1]);
            }
            #pragma unroll
            for (int sg = 0; sg < 2; ++sg) {
                int m = sB3 + 16*sg + l15;
                f32x4 v = f30[sg];
                *(uint2*)&sm.a.CC[m*16 + 4*l4] = make_uint2(pk2(v[0],v[1]), pk2(v[2],v[3]));
                if (l4 == 0) sm.a.SIG[m] = f31[sg][0];
            }
        }
        __syncthreads();

        // ========== G4': HC = relu(Wc1^T · [feat|ynm]^T + bc1) -> H1 ==========
        {
            short8 bcc[4];
            #pragma unroll
            for (int sg = 0; sg < 4; ++sg) {
                int m = smB + 16*sg + l15;
                if (l4 < 2) bcc[sg] = *(const short8*)&sm.a.CC[m*16 + 8*l4];
                else        bcc[sg] = *(const short8*)&sm.a.YNM[(m >> 6)*16 + 8*(l4 - 2)];
            }
            #pragma unroll
            for (int cg = 0; cg < 4; ++cg)
                #pragma unroll
                for (int sg = 0; sg < 4; ++sg) {
                    f32x4 v = MFMA16(wc1f[cg], bcc[sg],
                                     (f32x4){bc1r[cg][0], bc1r[cg][1], bc1r[cg][2], bc1r[cg][3]});
                    int m  = smB + 16*sg + l15;
                    int n0 = chB + 16*cg + 4*l4;
                    float r0 = fmaxf(v[0], 0.f), r1 = fmaxf(v[1], 0.f);
                    float r2 = fmaxf(v[2], 0.f), r3 = fmaxf(v[3], 0.f);
                    *(uint2*)&sm.a.H1[sw128(m, n0)] = make_uint2(pk2(r0,r1), pk2(r2,r3));
                }
        }
        __syncthreads();

        // ========== G5': color = sigmoid(Wc2^T · HC^T + bc2) -> COL ==========
        {
            f32x4 c5[2] = { (f32x4){0,0,0,0}, (f32x4){0,0,0,0} };
            #pragma unroll
            for (int kk = 0; kk < 4; ++kk) {
                short8 wc2fr = z8;
                if (l15 < 3) wc2fr = *(const short8*)&Wc2T3[l15*128 + kk*32 + 8*l4];
                #pragma unroll
                for (int sg = 0; sg < 2; ++sg) {
                    short8 b = *(const short8*)&sm.a.H1[sw128(sB3 + 16*sg + l15, kk*32 + 8*l4)];
                    c5[sg] = MFMA16(wc2fr, b, c5[sg]);
                }
            }
            if (l4 == 0) {
                #pragma unroll
                for (int sg = 0; sg < 2; ++sg) {
                    int m = sB3 + 16*sg + l15;
                    #pragma unroll
                    for (int vv = 0; vv < 3; ++vv)
                        sm.a.COL[m*4 + vv] = 1.f / (1.f + __expf(-(c5[sg][vv] + bc2r[vv])));
                }
            }
        }
        __syncthreads();

        if (wv < 2) Rp = raySetup(rays_o, rays_d, 2*g + wv, a0x,a0y,a0z,a1x,a1y,a1z);
        gp = g;
    }

    // trailing F for the last iteration
    if (gp >= 0 && wv < 2) {
        const RayP R = Rp;
        const int m = wv*64 + lane;
        float t  = R.tn + ((float)lane + 0.5f) * R.tstep;
        float px = fmaf(R.dx, t, R.ox);
        float py = fmaf(R.dy, t, R.oy);
        float pz = fmaf(R.dz, t, R.oz);
        float nx = fmaf(px - a0x, scx, -1.f);
        float ny = fmaf(py - a0y, scy, -1.f);
        float nz = fmaf(pz - a0z, scz, -1.f);
        bool ins = (nx >= -1.f) & (nx <= 1.f) & (ny >= -1.f) & (ny <= 1.f)
                 & (nz >= -1.f) & (nz <= 1.f);
        float sig = ins ? __expf(sm.a.SIG[m] + bdr) : 0.f;
        float delta = (lane == 63) ? (R.tf + 1.0f - t) : R.tstep;
        float tau = sig * delta * R.dnorm;
        float cum = tau;
        #pragma unroll
        for (int off = 1; off < 64; off <<= 1) {
            float tmp = __shfl_up(cum, off);
            if (lane >= off) cum += tmp;
        }
        float excl = cum - tau;
        float wgt = __expf(-excl) * (1.f - __expf(-tau));
        float c0 = wgt * sm.a.COL[m*4+0];
        float c1 = wgt * sm.a.COL[m*4+1];
        float c2 = wgt * sm.a.COL[m*4+2];
        float amv = wgt;
        float dmv = wgt * t;
        #pragma unroll
        for (int off = 32; off; off >>= 1) {
            c0  += __shfl_xor(c0,  off);
            c1  += __shfl_xor(c1,  off);
            c2  += __shfl_xor(c2,  off);
            amv += __shfl_xor(amv, off);
            dmv += __shfl_xor(dmv, off);
        }
        if (lane == 0) {
            float msk = R.act ? 1.f : 0.f;
            int ray = 2*gp + wv;
            out[ray*5+0] = c0*msk;
            out[ray*5+1] = c1*msk;
            out[ray*5+2] = c2*msk;
            out[ray*5+3] = amv*msk;
            out[ray*5+4] = dmv*msk;
        }
    }
}

extern "C" void kernel_launch(void* const* d_in, const int* in_sizes, int n_in,
                              void* d_out, int out_size, void* d_ws, size_t ws_size,
                              hipStream_t stream) {
    (void)in_sizes; (void)n_in; (void)d_ws; (void)ws_size; (void)out_size;
    const float* rays_o = (const float*)d_in[0];
    const float* rays_d = (const float*)d_in[1];
    const float* aabb   = (const float*)d_in[2];
    const float* W1  = (const float*)d_in[3];
    const float* b1  = (const float*)d_in[4];
    const float* W2  = (const float*)d_in[5];
    const float* b2  = (const float*)d_in[6];
    const float* Wd  = (const float*)d_in[7];
    const float* bd  = (const float*)d_in[8];
    const float* Wf  = (const float*)d_in[9];
    const float* bf  = (const float*)d_in[10];
    const float* Wc1 = (const float*)d_in[11];
    const float* bc1 = (const float*)d_in[12];
    const float* Wc2 = (const float*)d_in[13];
    const float* bc2 = (const float*)d_in[14];
    float* out = (float*)d_out;

    hipLaunchKernelGGL(RadianceRenderer_kernel, dim3(GRID), dim3(THREADS), 0, stream,
                       rays_o, rays_d, aabb, W1, b1, W2, b2, Wd, bd,
                       Wf, bf, Wc1, bc1, Wc2, bc2, out);
}

// Round 8
// 164.859 us; speedup vs baseline: 1.2065x; 1.0793x over previous
//
#include <hip/hip_runtime.h>
#include <math.h>

#define THREADS 256
#define GRID 512
#define NRAYS 8192
#define FAR_T 10.0f
#define CSTR 24   // CC row stride in shorts (48 B: 16B-aligned, 8 distinct bank-pairs)

typedef __attribute__((ext_vector_type(8))) short short8;
typedef __attribute__((ext_vector_type(4))) float f32x4;

static __device__ __forceinline__ unsigned f2bfu(float f) {
    unsigned u = __builtin_bit_cast(unsigned, f);
    return (u + 0x7fffu + ((u >> 16) & 1u)) >> 16;
}
// fast bf16x2 pack: round-half-up + v_perm_b32 byte select (3 VALU ops)
static __device__ __forceinline__ unsigned pk2(float a, float b) {
    unsigned ra = __builtin_bit_cast(unsigned, a) + 0x8000u;
    unsigned rb = __builtin_bit_cast(unsigned, b) + 0x8000u;
    return __builtin_amdgcn_perm(rb, ra, 0x07060302u);
}
static __device__ __forceinline__ int sw128(int r, int k) { return (r << 7) + (k ^ ((r & 7) << 3)); }
static __device__ __forceinline__ int sw32(int r, int k)  { return (r << 5) + (k ^ ((r & 3) << 3)); }
static __device__ __forceinline__ f32x4 MFMA16(short8 a, short8 b, f32x4 c) {
    return __builtin_amdgcn_mfma_f32_16x16x32_bf16(a, b, c, 0, 0, 0);
}

struct RayP { float ox,oy,oz,dx,dy,dz,tn,tf,tstep,dnorm; bool act; };

static __device__ __forceinline__ RayP raySetup(const float* __restrict__ ro, const float* __restrict__ rd,
        int r, float a0x,float a0y,float a0z,float a1x,float a1y,float a1z) {
    RayP R;
    R.ox=ro[3*r+0]; R.oy=ro[3*r+1]; R.oz=ro[3*r+2];
    R.dx=rd[3*r+0]; R.dy=rd[3*r+1]; R.dz=rd[3*r+2];
    float ivx=1.f/R.dx, ivy=1.f/R.dy, ivz=1.f/R.dz;
    float t1x=(a0x-R.ox)*ivx, t2x=(a1x-R.ox)*ivx;
    float t1y=(a0y-R.oy)*ivy, t2y=(a1y-R.oy)*ivy;
    float t1z=(a0z-R.oz)*ivz, t2z=(a1z-R.oz)*ivz;
    float tn = fmaxf(fmaxf(fminf(t1x,t2x),fminf(t1y,t2y)),fminf(t1z,t2z));
    tn = fmaxf(tn, 0.f);
    float tf = fminf(fminf(fmaxf(t1x,t2x),fmaxf(t1y,t2y)),fmaxf(t1z,t2z));
    tf = fminf(tf, FAR_T);
    R.act = tn < tf;
    R.tn = R.act ? tn : 0.f;
    R.tf = R.act ? tf : 1.f;
    R.tstep = (R.tf - R.tn) * (1.f/64.f);
    R.dnorm = sqrtf(R.dx*R.dx + R.dy*R.dy + R.dz*R.dz);
    return R;
}

__global__ __launch_bounds__(THREADS)
__attribute__((amdgpu_waves_per_eu(2, 2), amdgpu_num_vgpr(256)))
void RadianceRenderer_kernel(const float* __restrict__ rays_o, const float* __restrict__ rays_d,
                             const float* __restrict__ aabb,
                             const float* __restrict__ W1, const float* __restrict__ b1,
                             const float* __restrict__ W2, const float* __restrict__ b2,
                             const float* __restrict__ Wd, const float* __restrict__ bd,
                             const float* __restrict__ Wf, const float* __restrict__ bf,
                             const float* __restrict__ Wc1, const float* __restrict__ bc1,
                             const float* __restrict__ Wc2, const float* __restrict__ bc2,
                             float* __restrict__ out)
{
    // persistent small weights (7.1 KB) — read per-iteration via predicated ds_read
    __shared__ __align__(16) short W1T[128*8];      // [ch][k0..7]: k<3=W1, k==3=b1, k>=4=0
    __shared__ __align__(16) short Wfd17[17*128];   // sw128: rows 0-15 = Wf cols, row 16 = Wd
    __shared__ __align__(16) short Wc2T3[3*128];    // linear: row c (<3) = Wc2 col c
    // big weights staged once into regs; staging region aliases activations (74.3 KB)
    __shared__ __align__(16) union {
        struct { short W2T[128*128]; short Wc1T[128*32]; } w;                    // 40 KB
        struct { short H1[128*128]; short H2[128*128]; short CC[128*CSTR];
                 short YNM[2*16]; float SIG[128]; float COL[128*4]; } a;
    } sm;

    const int tid  = threadIdx.x;
    const int lane = tid & 63;
    const int wv   = tid >> 6;
    const int l15  = lane & 15;
    const int l4   = lane >> 4;
    const short8 z8 = {0,0,0,0,0,0,0,0};

    // ---- stage weights ----
    for (int i = tid; i < 128*128; i += THREADS) {
        int k = i >> 7, n = i & 127;
        sm.w.W2T[sw128(n, k)] = (short)f2bfu(W2[i]);
    }
    for (int i = tid; i < 128*32; i += THREADS) {
        int n = i >> 5, k = i & 31;
        sm.w.Wc1T[sw32(n, k)] = (short)f2bfu(Wc1[k*128 + n]);
    }
    for (int i = tid; i < 17*128; i += THREADS) {
        int n = i >> 7, k = i & 127;
        float v = (n < 16) ? Wf[k*16 + n] : Wd[k];
        Wfd17[sw128(n, k)] = (short)f2bfu(v);
    }
    for (int i = tid; i < 3*128; i += THREADS) {
        int c = i >> 7, k = i & 127;
        Wc2T3[i] = (short)f2bfu(Wc2[k*3 + c]);
    }
    for (int i = tid; i < 128*8; i += THREADS) {
        int ch = i >> 3, k = i & 7;
        float f = (k < 3) ? W1[k*128 + ch] : ((k == 3) ? b1[ch] : 0.f);
        W1T[i] = (short)f2bfu(f);
    }
    __syncthreads();

    const int chB = (wv >> 1) * 64;
    const int smB = (wv & 1) * 64;
    const int sB3 = wv * 32;

    // register-resident: only the two big weight matrices
    short8 w2f[4][4], wc1f[4];
    #pragma unroll
    for (int jn = 0; jn < 4; ++jn)
        #pragma unroll
        for (int kk = 0; kk < 4; ++kk)
            w2f[jn][kk] = *(const short8*)&sm.w.W2T[sw128(chB + 16*jn + l15, kk*32 + 8*l4)];
    #pragma unroll
    for (int cg = 0; cg < 4; ++cg)
        wc1f[cg] = *(const short8*)&sm.w.Wc1T[sw32(chB + 16*cg + l15, 8*l4)];

    float b2r[4][4], bc1r[4][4];
    #pragma unroll
    for (int jn = 0; jn < 4; ++jn)
        #pragma unroll
        for (int vv = 0; vv < 4; ++vv) {
            b2r[jn][vv]  = b2[chB + 16*jn + 4*l4 + vv];
            bc1r[jn][vv] = bc1[chB + 16*jn + 4*l4 + vv];
        }
    f32x4 bfv;
    #pragma unroll
    for (int vv = 0; vv < 4; ++vv) bfv[vv] = bf[4*l4 + vv];
    float bc2r[3] = { bc2[0], bc2[1], bc2[2] };
    const float bdr = bd[0];

    const float a0x=aabb[0],a0y=aabb[1],a0z=aabb[2],a1x=aabb[3],a1y=aabb[4],a1z=aabb[5];
    const float scx=2.f/(a1x-a0x), scy=2.f/(a1y-a0y), scz=2.f/(a1z-a0z);

    __syncthreads();   // staging reads done before Act writes

    // zero CC once: first L1 reads CC cols 4..7 before G3' ever writes them
    for (int i = tid; i < 128*CSTR/2; i += THREADS) ((unsigned*)sm.a.CC)[i] = 0u;
    __syncthreads();

    int gp = -1;
    RayP Rp;

    for (int g = blockIdx.x; g < NRAYS/2; g += gridDim.x) {
        // ========== A0 (waves 2,3): xyz rows + per-ray ynm  ||  F(gp) (waves 0,1) ==========
        if (wv >= 2) {
            const int m   = tid - 128;          // sample row 0..127
            const int ray = 2*g + (m >> 6);
            RayP R = raySetup(rays_o, rays_d, ray, a0x,a0y,a0z,a1x,a1y,a1z);
            const int s = m & 63;
            float t  = R.tn + ((float)s + 0.5f) * R.tstep;
            float px = fmaf(R.dx, t, R.ox);
            float py = fmaf(R.dy, t, R.oy);
            float pz = fmaf(R.dz, t, R.oz);
            float nx = fmaf(px - a0x, scx, -1.f);
            float ny = fmaf(py - a0y, scy, -1.f);
            float nz = fmaf(pz - a0z, scz, -1.f);
            *(uint2*)&sm.a.CC[m*CSTR] = make_uint2(pk2(nx, ny), pk2(nz, 1.0f));
            if (s == 0) {   // one thread per ray writes ynm (16 bf16)
                float inorm = 1.f / R.dnorm;
                float x = R.dx*inorm, y = R.dy*inorm, z = R.dz*inorm;
                float x2 = x*x, y2 = y*y, z2 = z*z;
                unsigned q0 = pk2(0.282094791773878f,              -0.488602511902920f*y);
                unsigned q1 = pk2(0.488602511902920f*z,            -0.488602511902920f*x);
                unsigned q2 = pk2(1.092548430592079f*x*y,          -1.092548430592079f*y*z);
                unsigned q3 = pk2(0.315391565252520f*(3.f*z2-1.f), -1.092548430592079f*x*z);
                unsigned q4 = pk2(0.546274215296040f*(x2-y2),      -0.590043589926644f*y*(3.f*x2-y2));
                unsigned q5 = pk2(2.890611442640554f*x*y*z,        -0.457045799464466f*y*(5.f*z2-1.f));
                unsigned q6 = pk2(0.373176332590115f*z*(5.f*z2-3.f), -0.457045799464466f*x*(5.f*z2-1.f));
                unsigned q7 = pk2(1.445305721320277f*z*(x2-y2),    -0.590043589926644f*x*(x2-3.f*y2));
                *(uint4*)&sm.a.YNM[(m >> 6)*16    ] = make_uint4(q0,q1,q2,q3);
                *(uint4*)&sm.a.YNM[(m >> 6)*16 + 8] = make_uint4(q4,q5,q6,q7);
            }
        } else if (gp >= 0) {
            // ========== F: transmittance integration for previous iteration ==========
            const RayP R = Rp;
            const int m = wv*64 + lane;
            const int mx = (m >> 2) & 3;   // COL bank-spread key
            float t  = R.tn + ((float)lane + 0.5f) * R.tstep;
            float px = fmaf(R.dx, t, R.ox);
            float py = fmaf(R.dy, t, R.oy);
            float pz = fmaf(R.dz, t, R.oz);
            float nx = fmaf(px - a0x, scx, -1.f);
            float ny = fmaf(py - a0y, scy, -1.f);
            float nz = fmaf(pz - a0z, scz, -1.f);
            bool ins = (nx >= -1.f) & (nx <= 1.f) & (ny >= -1.f) & (ny <= 1.f)
                     & (nz >= -1.f) & (nz <= 1.f);
            float sig = ins ? __expf(sm.a.SIG[m] + bdr) : 0.f;
            float delta = (lane == 63) ? (R.tf + 1.0f - t) : R.tstep;
            float tau = sig * delta * R.dnorm;
            float cum = tau;
            #pragma unroll
            for (int off = 1; off < 64; off <<= 1) {
                float tmp = __shfl_up(cum, off);
                if (lane >= off) cum += tmp;
            }
            float excl = cum - tau;
            float wgt = __expf(-excl) * (1.f - __expf(-tau));
            float c0 = wgt * sm.a.COL[m*4 + (0 ^ mx)];
            float c1 = wgt * sm.a.COL[m*4 + (1 ^ mx)];
            float c2 = wgt * sm.a.COL[m*4 + (2 ^ mx)];
            float amv = wgt;
            float dmv = wgt * t;
            #pragma unroll
            for (int off = 32; off; off >>= 1) {
                c0  += __shfl_xor(c0,  off);
                c1  += __shfl_xor(c1,  off);
                c2  += __shfl_xor(c2,  off);
                amv += __shfl_xor(amv, off);
                dmv += __shfl_xor(dmv, off);
            }
            if (lane == 0) {
                float msk = R.act ? 1.f : 0.f;
                int ray = 2*gp + wv;
                out[ray*5+0] = c0*msk;
                out[ray*5+1] = c1*msk;
                out[ray*5+2] = c2*msk;
                out[ray*5+3] = amv*msk;
                out[ray*5+4] = dmv*msk;
            }
        }
        __syncthreads();

        // ========== L1 (MFMA): H1 = relu(W1ext^T · XYZ^T), bias via k=3 const-1 ==========
        {
            short8 bx[4];
            #pragma unroll
            for (int im = 0; im < 4; ++im) {
                short8 v = z8;
                if (l4 == 0) v = *(const short8*)&sm.a.CC[(smB + 16*im + l15)*CSTR];
                bx[im] = v;
            }
            #pragma unroll
            for (int jn = 0; jn < 4; ++jn) {
                short8 w1fr = z8;
                if (l4 == 0) w1fr = *(const short8*)&W1T[(chB + 16*jn + l15)*8];
                #pragma unroll
                for (int im = 0; im < 4; ++im) {
                    f32x4 v = MFMA16(w1fr, bx[im], (f32x4){0.f,0.f,0.f,0.f});
                    int m  = smB + 16*im + l15;
                    int n0 = chB + 16*jn + 4*l4;
                    float r0 = fmaxf(v[0], 0.f), r1 = fmaxf(v[1], 0.f);
                    float r2 = fmaxf(v[2], 0.f), r3 = fmaxf(v[3], 0.f);
                    *(uint2*)&sm.a.H1[sw128(m, n0)] = make_uint2(pk2(r0,r1), pk2(r2,r3));
                }
            }
        }
        __syncthreads();

        // ========== L2': H2 = relu(W2^T · H1^T + b2) — acc init with bias ==========
        {
            f32x4 acc[4][4];
            #pragma unroll
            for (int jn = 0; jn < 4; ++jn)
                #pragma unroll
                for (int im = 0; im < 4; ++im)
                    acc[jn][im] = (f32x4){b2r[jn][0], b2r[jn][1], b2r[jn][2], b2r[jn][3]};
            #pragma unroll
            for (int kk = 0; kk < 4; ++kk) {
                short8 bfr[4];
                #pragma unroll
                for (int im = 0; im < 4; ++im)
                    bfr[im] = *(const short8*)&sm.a.H1[sw128(smB + 16*im + l15, kk*32 + 8*l4)];
                #pragma unroll
                for (int jn = 0; jn < 4; ++jn)
                    #pragma unroll
                    for (int im = 0; im < 4; ++im)
                        acc[jn][im] = MFMA16(w2f[jn][kk], bfr[im], acc[jn][im]);
            }
            #pragma unroll
            for (int jn = 0; jn < 4; ++jn)
                #pragma unroll
                for (int im = 0; im < 4; ++im) {
                    int m  = smB + 16*im + l15;
                    int n0 = chB + 16*jn + 4*l4;
                    f32x4 v = acc[jn][im];
                    float r0 = fmaxf(v[0], 0.f), r1 = fmaxf(v[1], 0.f);
                    float r2 = fmaxf(v[2], 0.f), r3 = fmaxf(v[3], 0.f);
                    *(uint2*)&sm.a.H2[sw128(m, n0)] = make_uint2(pk2(r0,r1), pk2(r2,r3));
                }
        }
        __syncthreads();

        // ========== G3': feat(+bf) -> CC[:,0:16], sigma-dot -> SIG ==========
        {
            f32x4 f30[2] = { bfv, bfv };                              // feat acc (bias-init)
            f32x4 f31[2] = { (f32x4){0,0,0,0}, (f32x4){0,0,0,0} };    // sigma acc
            #pragma unroll
            for (int kk = 0; kk < 4; ++kk) {
                short8 bA = *(const short8*)&sm.a.H2[sw128(sB3 +      l15, kk*32 + 8*l4)];
                short8 bB = *(const short8*)&sm.a.H2[sw128(sB3 + 16 + l15, kk*32 + 8*l4)];
                short8 wfd0 = *(const short8*)&Wfd17[sw128(l15, kk*32 + 8*l4)];
                short8 wfd1 = z8;
                if (l15 == 0) wfd1 = *(const short8*)&Wfd17[sw128(16, kk*32 + 8*l4)];
                f30[0] = MFMA16(wfd0, bA, f30[0]);
                f30[1] = MFMA16(wfd0, bB, f30[1]);
                f31[0] = MFMA16(wfd1, bA, f31[0]);
                f31[1] = MFMA16(wfd1, bB, f31[1]);
            }
            #pragma unroll
            for (int sg = 0; sg < 2; ++sg) {
                int m = sB3 + 16*sg + l15;
                f32x4 v = f30[sg];
                *(uint2*)&sm.a.CC[m*CSTR + 4*l4] = make_uint2(pk2(v[0],v[1]), pk2(v[2],v[3]));
                if (l4 == 0) sm.a.SIG[m] = f31[sg][0];
            }
        }
        __syncthreads();

        // ========== G4': HC = relu(Wc1^T · [feat|ynm]^T + bc1) -> H1 ==========
        {
            short8 bcc[4];
            #pragma unroll
            for (int sg = 0; sg < 4; ++sg) {
                int m = smB + 16*sg + l15;
                if (l4 < 2) bcc[sg] = *(const short8*)&sm.a.CC[m*CSTR + 8*l4];
                else        bcc[sg] = *(const short8*)&sm.a.YNM[(m >> 6)*16 + 8*(l4 - 2)];
            }
            #pragma unroll
            for (int cg = 0; cg < 4; ++cg)
                #pragma unroll
                for (int sg = 0; sg < 4; ++sg) {
                    f32x4 v = MFMA16(wc1f[cg], bcc[sg],
                                     (f32x4){bc1r[cg][0], bc1r[cg][1], bc1r[cg][2], bc1r[cg][3]});
                    int m  = smB + 16*sg + l15;
                    int n0 = chB + 16*cg + 4*l4;
                    float r0 = fmaxf(v[0], 0.f), r1 = fmaxf(v[1], 0.f);
                    float r2 = fmaxf(v[2], 0.f), r3 = fmaxf(v[3], 0.f);
                    *(uint2*)&sm.a.H1[sw128(m, n0)] = make_uint2(pk2(r0,r1), pk2(r2,r3));
                }
        }
        __syncthreads();

        // ========== G5': color = sigmoid(Wc2^T · HC^T + bc2) -> COL ==========
        {
            f32x4 c5[2] = { (f32x4){0,0,0,0}, (f32x4){0,0,0,0} };
            #pragma unroll
            for (int kk = 0; kk < 4; ++kk) {
                short8 wc2fr = z8;
                if (l15 < 3) wc2fr = *(const short8*)&Wc2T3[l15*128 + kk*32 + 8*l4];
                #pragma unroll
                for (int sg = 0; sg < 2; ++sg) {
                    short8 b = *(const short8*)&sm.a.H1[sw128(sB3 + 16*sg + l15, kk*32 + 8*l4)];
                    c5[sg] = MFMA16(wc2fr, b, c5[sg]);
                }
            }
            if (l4 == 0) {
                #pragma unroll
                for (int sg = 0; sg < 2; ++sg) {
                    int m = sB3 + 16*sg + l15;
                    int mx = (m >> 2) & 3;
                    #pragma unroll
                    for (int vv = 0; vv < 3; ++vv)
                        sm.a.COL[m*4 + (vv ^ mx)] = 1.f / (1.f + __expf(-(c5[sg][vv] + bc2r[vv])));
                }
            }
        }
        __syncthreads();

        if (wv < 2) Rp = raySetup(rays_o, rays_d, 2*g + wv, a0x,a0y,a0z,a1x,a1y,a1z);
        gp = g;
    }

    // trailing F for the last iteration
    if (gp >= 0 && wv < 2) {
        const RayP R = Rp;
        const int m = wv*64 + lane;
        const int mx = (m >> 2) & 3;
        float t  = R.tn + ((float)lane + 0.5f) * R.tstep;
        float px = fmaf(R.dx, t, R.ox);
        float py = fmaf(R.dy, t, R.oy);
        float pz = fmaf(R.dz, t, R.oz);
        float nx = fmaf(px - a0x, scx, -1.f);
        float ny = fmaf(py - a0y, scy, -1.f);
        float nz = fmaf(pz - a0z, scz, -1.f);
        bool ins = (nx >= -1.f) & (nx <= 1.f) & (ny >= -1.f) & (ny <= 1.f)
                 & (nz >= -1.f) & (nz <= 1.f);
        float sig = ins ? __expf(sm.a.SIG[m] + bdr) : 0.f;
        float delta = (lane == 63) ? (R.tf + 1.0f - t) : R.tstep;
        float tau = sig * delta * R.dnorm;
        float cum = tau;
        #pragma unroll
        for (int off = 1; off < 64; off <<= 1) {
            float tmp = __shfl_up(cum, off);
            if (lane >= off) cum += tmp;
        }
        float excl = cum - tau;
        float wgt = __expf(-excl) * (1.f - __expf(-tau));
        float c0 = wgt * sm.a.COL[m*4 + (0 ^ mx)];
        float c1 = wgt * sm.a.COL[m*4 + (1 ^ mx)];
        float c2 = wgt * sm.a.COL[m*4 + (2 ^ mx)];
        float amv = wgt;
        float dmv = wgt * t;
        #pragma unroll
        for (int off = 32; off; off >>= 1) {
            c0  += __shfl_xor(c0,  off);
            c1  += __shfl_xor(c1,  off);
            c2  += __shfl_xor(c2,  off);
            amv += __shfl_xor(amv, off);
            dmv += __shfl_xor(dmv, off);
        }
        if (lane == 0) {
            float msk = R.act ? 1.f : 0.f;
            int ray = 2*gp + wv;
            out[ray*5+0] = c0*msk;
            out[ray*5+1] = c1*msk;
            out[ray*5+2] = c2*msk;
            out[ray*5+3] = amv*msk;
            out[ray*5+4] = dmv*msk;
        }
    }
}

extern "C" void kernel_launch(void* const* d_in, const int* in_sizes, int n_in,
                              void* d_out, int out_size, void* d_ws, size_t ws_size,
                              hipStream_t stream) {
    (void)in_sizes; (void)n_in; (void)d_ws; (void)ws_size; (void)out_size;
    const float* rays_o = (const float*)d_in[0];
    const float* rays_d = (const float*)d_in[1];
    const float* aabb   = (const float*)d_in[2];
    const float* W1  = (const float*)d_in[3];
    const float* b1  = (const float*)d_in[4];
    const float* W2  = (const float*)d_in[5];
    const float* b2  = (const float*)d_in[6];
    const float* Wd  = (const float*)d_in[7];
    const float* bd  = (const float*)d_in[8];
    const float* Wf  = (const float*)d_in[9];
    const float* bf  = (const float*)d_in[10];
    const float* Wc1 = (const float*)d_in[11];
    const float* bc1 = (const float*)d_in[12];
    const float* Wc2 = (const float*)d_in[13];
    const float* bc2 = (const float*)d_in[14];
    float* out = (float*)d_out;

    hipLaunchKernelGGL(RadianceRenderer_kernel, dim3(GRID), dim3(THREADS), 0, stream,
                       rays_o, rays_d, aabb, W1, b1, W2, b2, Wd, bd,
                       Wf, bf, Wc1, bc1, Wc2, bc2, out);
}

// Round 9
// 147.860 us; speedup vs baseline: 1.3452x; 1.1150x over previous
//
#include <hip/hip_runtime.h>
#include <math.h>

#define THREADS 512
#define GRID 512
#define NRAYS 8192
#define FAR_T 10.0f
#define CSTR 24   // CC row stride in shorts (48 B rows; cols 0-15 data, 16-23 ynm/pad)

typedef __attribute__((ext_vector_type(8))) short short8;
typedef __attribute__((ext_vector_type(4))) float f32x4;

static __device__ __forceinline__ unsigned f2bfu(float f) {
    unsigned u = __builtin_bit_cast(unsigned, f);
    return (u + 0x7fffu + ((u >> 16) & 1u)) >> 16;
}
// fast bf16x2 pack: round-half-up + v_perm_b32 byte select
static __device__ __forceinline__ unsigned pk2(float a, float b) {
    unsigned ra = __builtin_bit_cast(unsigned, a) + 0x8000u;
    unsigned rb = __builtin_bit_cast(unsigned, b) + 0x8000u;
    return __builtin_amdgcn_perm(rb, ra, 0x07060302u);
}
static __device__ __forceinline__ int sw128(int r, int k) { return (r << 7) + (k ^ ((r & 7) << 3)); }
static __device__ __forceinline__ int sw32(int r, int k)  { return (r << 5) + (k ^ ((r & 3) << 3)); }
static __device__ __forceinline__ f32x4 MFMA16(short8 a, short8 b, f32x4 c) {
    return __builtin_amdgcn_mfma_f32_16x16x32_bf16(a, b, c, 0, 0, 0);
}

struct RayP { float ox,oy,oz,dx,dy,dz,tn,tf,tstep,dnorm; bool act; };

static __device__ __forceinline__ RayP raySetup(const float* __restrict__ ro, const float* __restrict__ rd,
        int r, float a0x,float a0y,float a0z,float a1x,float a1y,float a1z) {
    RayP R;
    R.ox=ro[3*r+0]; R.oy=ro[3*r+1]; R.oz=ro[3*r+2];
    R.dx=rd[3*r+0]; R.dy=rd[3*r+1]; R.dz=rd[3*r+2];
    float ivx=1.f/R.dx, ivy=1.f/R.dy, ivz=1.f/R.dz;
    float t1x=(a0x-R.ox)*ivx, t2x=(a1x-R.ox)*ivx;
    float t1y=(a0y-R.oy)*ivy, t2y=(a1y-R.oy)*ivy;
    float t1z=(a0z-R.oz)*ivz, t2z=(a1z-R.oz)*ivz;
    float tn = fmaxf(fmaxf(fminf(t1x,t2x),fminf(t1y,t2y)),fminf(t1z,t2z));
    tn = fmaxf(tn, 0.f);
    float tf = fminf(fminf(fmaxf(t1x,t2x),fmaxf(t1y,t2y)),fmaxf(t1z,t2z));
    tf = fminf(tf, FAR_T);
    R.act = tn < tf;
    R.tn = R.act ? tn : 0.f;
    R.tf = R.act ? tf : 1.f;
    R.tstep = (R.tf - R.tn) * (1.f/64.f);
    R.dnorm = sqrtf(R.dx*R.dx + R.dy*R.dy + R.dz*R.dz);
    return R;
}

__global__ __launch_bounds__(THREADS, 4)   // 4 waves/EU min -> 128-VGPR budget, 2 blocks/CU
void RadianceRenderer_kernel(const float* __restrict__ rays_o, const float* __restrict__ rays_d,
                             const float* __restrict__ aabb,
                             const float* __restrict__ W1, const float* __restrict__ b1,
                             const float* __restrict__ W2, const float* __restrict__ b2,
                             const float* __restrict__ Wd, const float* __restrict__ bd,
                             const float* __restrict__ Wf, const float* __restrict__ bf,
                             const float* __restrict__ Wc1, const float* __restrict__ bc1,
                             const float* __restrict__ Wc2, const float* __restrict__ bc2,
                             float* __restrict__ out)
{
    // persistent small weights + biases (8 KB)
    __shared__ __align__(16) short W1T[128*8];      // [ch][k0..7]: k<3=W1, k==3=b1, k>=4=0
    __shared__ __align__(16) short Wfd17[17*128];   // sw128: rows 0-15=Wf cols, row 16=Wd
    __shared__ __align__(16) short Wc2T3[3*128];    // linear: row c(<3) = Wc2 col c
    __shared__ __align__(16) float B2F[128];        // b2 (f32)
    __shared__ __align__(16) float BC1F[128];       // bc1 (f32)
    // big weights staged once into regs; staging aliases activations (72 KB)
    __shared__ __align__(16) union {
        struct { short W2T[128*128]; short Wc1T[128*32]; } w;                  // 40 KB
        struct { short H1[128*128]; short H2[128*128];
                 short CC[128*CSTR];          // cols 0-15 xyz/feat, 16-23 ynm(rows 0,1,64,65)
                 float CS[4*128]; } a;        // rows 0-2 color, row 3 sigma-dot
    } sm;
    // total: 8192 + 73728 = 81920 B exactly -> 2 blocks/CU

    const int tid  = threadIdx.x;
    const int lane = tid & 63;
    const int wv   = tid >> 6;        // wave 0..7
    const int l15  = lane & 15;
    const int l4   = lane >> 4;
    const short8 z8 = {0,0,0,0,0,0,0,0};

    // ---- stage weights ----
    for (int i = tid; i < 128*128; i += THREADS) {
        int k = i >> 7, n = i & 127;
        sm.w.W2T[sw128(n, k)] = (short)f2bfu(W2[i]);
    }
    for (int i = tid; i < 128*32; i += THREADS) {
        int n = i >> 5, k = i & 31;
        sm.w.Wc1T[sw32(n, k)] = (short)f2bfu(Wc1[k*128 + n]);
    }
    for (int i = tid; i < 17*128; i += THREADS) {
        int n = i >> 7, k = i & 127;
        float v = (n < 16) ? Wf[k*16 + n] : Wd[k];
        Wfd17[sw128(n, k)] = (short)f2bfu(v);
    }
    for (int i = tid; i < 3*128; i += THREADS) {
        int c = i >> 7, k = i & 127;
        Wc2T3[i] = (short)f2bfu(Wc2[k*3 + c]);
    }
    for (int i = tid; i < 128*8; i += THREADS) {
        int ch = i >> 3, k = i & 7;
        float f = (k < 3) ? W1[k*128 + ch] : ((k == 3) ? b1[ch] : 0.f);
        W1T[i] = (short)f2bfu(f);
    }
    for (int i = tid; i < 128; i += THREADS) { B2F[i] = b2[i]; BC1F[i] = bc1[i]; }
    __syncthreads();

    const int chB = (wv >> 1) * 32;   // channel slice (L1/L2'/G4')
    const int smB = (wv & 1) * 64;    // sample slice  (L1/L2'/G4')
    const int sB3 = wv * 16;          // sample slice  (G3'/G5')

    // register-resident big weights (w2f 32 + wc1f 8 = 40 VGPR)
    short8 w2f[2][4], wc1f[2];
    #pragma unroll
    for (int jn = 0; jn < 2; ++jn)
        #pragma unroll
        for (int kk = 0; kk < 4; ++kk)
            w2f[jn][kk] = *(const short8*)&sm.w.W2T[sw128(chB + 16*jn + l15, kk*32 + 8*l4)];
    #pragma unroll
    for (int cg = 0; cg < 2; ++cg)
        wc1f[cg] = *(const short8*)&sm.w.Wc1T[sw32(chB + 16*cg + l15, 8*l4)];

    f32x4 bfv;
    #pragma unroll
    for (int vv = 0; vv < 4; ++vv) bfv[vv] = bf[4*l4 + vv];
    float bc2r[3] = { bc2[0], bc2[1], bc2[2] };
    const float bdr = bd[0];

    const float a0x=aabb[0],a0y=aabb[1],a0z=aabb[2],a1x=aabb[3],a1y=aabb[4],a1z=aabb[5];
    const float scx=2.f/(a1x-a0x), scy=2.f/(a1y-a0y), scz=2.f/(a1z-a0z);

    __syncthreads();   // staging reads done before Act writes

    // zero CC once (L1 reads cols 4..7 before G3' writes them; avoid NaN bf16 junk)
    for (int i = tid; i < 128*CSTR/2; i += THREADS) ((unsigned*)sm.a.CC)[i] = 0u;
    __syncthreads();

    int gp = -1;

    for (int g = blockIdx.x; g < NRAYS/2; g += gridDim.x) {
        // ===== A0 (waves 4,5): xyz rows + per-ray ynm  ||  F(gp) (waves 0,1) =====
        if (wv == 4 || wv == 5) {
            const int m   = tid - 256;          // sample row 0..127
            const int ray = 2*g + (m >> 6);
            RayP R = raySetup(rays_o, rays_d, ray, a0x,a0y,a0z,a1x,a1y,a1z);
            const int s = m & 63;
            float t  = R.tn + ((float)s + 0.5f) * R.tstep;
            float px = fmaf(R.dx, t, R.ox);
            float py = fmaf(R.dy, t, R.oy);
            float pz = fmaf(R.dz, t, R.oz);
            float nx = fmaf(px - a0x, scx, -1.f);
            float ny = fmaf(py - a0y, scy, -1.f);
            float nz = fmaf(pz - a0z, scz, -1.f);
            *(uint2*)&sm.a.CC[m*CSTR] = make_uint2(pk2(nx, ny), pk2(nz, 1.0f));
            if (s == 0) {   // one thread per ray writes ynm into CC cols 16-23, rows m..m+1
                float inorm = 1.f / R.dnorm;
                float x = R.dx*inorm, y = R.dy*inorm, z = R.dz*inorm;
                float x2 = x*x, y2 = y*y, z2 = z*z;
                unsigned q0 = pk2(0.282094791773878f,              -0.488602511902920f*y);
                unsigned q1 = pk2(0.488602511902920f*z,            -0.488602511902920f*x);
                unsigned q2 = pk2(1.092548430592079f*x*y,          -1.092548430592079f*y*z);
                unsigned q3 = pk2(0.315391565252520f*(3.f*z2-1.f), -1.092548430592079f*x*z);
                unsigned q4 = pk2(0.546274215296040f*(x2-y2),      -0.590043589926644f*y*(3.f*x2-y2));
                unsigned q5 = pk2(2.890611442640554f*x*y*z,        -0.457045799464466f*y*(5.f*z2-1.f));
                unsigned q6 = pk2(0.373176332590115f*z*(5.f*z2-3.f), -0.457045799464466f*x*(5.f*z2-1.f));
                unsigned q7 = pk2(1.445305721320277f*z*(x2-y2),    -0.590043589926644f*x*(x2-3.f*y2));
                *(uint4*)&sm.a.CC[m*CSTR + 16]        = make_uint4(q0,q1,q2,q3);
                *(uint4*)&sm.a.CC[(m+1)*CSTR + 16]    = make_uint4(q4,q5,q6,q7);
            }
        } else if (wv < 2 && gp >= 0) {
            // ===== F: transmittance integration for previous iteration =====
            RayP R = raySetup(rays_o, rays_d, 2*gp + wv, a0x,a0y,a0z,a1x,a1y,a1z);
            const int m = wv*64 + lane;
            float t  = R.tn + ((float)lane + 0.5f) * R.tstep;
            float px = fmaf(R.dx, t, R.ox);
            float py = fmaf(R.dy, t, R.oy);
            float pz = fmaf(R.dz, t, R.oz);
            float nx = fmaf(px - a0x, scx, -1.f);
            float ny = fmaf(py - a0y, scy, -1.f);
            float nz = fmaf(pz - a0z, scz, -1.f);
            bool ins = (nx >= -1.f) & (nx <= 1.f) & (ny >= -1.f) & (ny <= 1.f)
                     & (nz >= -1.f) & (nz <= 1.f);
            float sig = ins ? __expf(sm.a.CS[3*128 + m] + bdr) : 0.f;
            float delta = (lane == 63) ? (R.tf + 1.0f - t) : R.tstep;
            float tau = sig * delta * R.dnorm;
            float cum = tau;
            #pragma unroll
            for (int off = 1; off < 64; off <<= 1) {
                float tmp = __shfl_up(cum, off);
                if (lane >= off) cum += tmp;
            }
            float excl = cum - tau;
            float wgt = __expf(-excl) * (1.f - __expf(-tau));
            float c0 = wgt * sm.a.CS[0*128 + m];
            float c1 = wgt * sm.a.CS[1*128 + m];
            float c2 = wgt * sm.a.CS[2*128 + m];
            float amv = wgt;
            float dmv = wgt * t;
            #pragma unroll
            for (int off = 32; off; off >>= 1) {
                c0  += __shfl_xor(c0,  off);
                c1  += __shfl_xor(c1,  off);
                c2  += __shfl_xor(c2,  off);
                amv += __shfl_xor(amv, off);
                dmv += __shfl_xor(dmv, off);
            }
            if (lane == 0) {
                float msk = R.act ? 1.f : 0.f;
                int ray = 2*gp + wv;
                out[ray*5+0] = c0*msk;
                out[ray*5+1] = c1*msk;
                out[ray*5+2] = c2*msk;
                out[ray*5+3] = amv*msk;
                out[ray*5+4] = dmv*msk;
            }
        }
        __syncthreads();

        // ===== L1 (MFMA): H1 = relu(W1ext^T · XYZ^T), bias via k=3 const-1 =====
        {
            short8 bx[4];
            #pragma unroll
            for (int im = 0; im < 4; ++im) {
                short8 v = z8;
                if (l4 == 0) v = *(const short8*)&sm.a.CC[(smB + 16*im + l15)*CSTR];
                bx[im] = v;
            }
            #pragma unroll
            for (int jn = 0; jn < 2; ++jn) {
                short8 w1fr = z8;
                if (l4 == 0) w1fr = *(const short8*)&W1T[(chB + 16*jn + l15)*8];
                #pragma unroll
                for (int im = 0; im < 4; ++im) {
                    f32x4 v = MFMA16(w1fr, bx[im], (f32x4){0.f,0.f,0.f,0.f});
                    int m  = smB + 16*im + l15;
                    int n0 = chB + 16*jn + 4*l4;
                    float r0 = fmaxf(v[0], 0.f), r1 = fmaxf(v[1], 0.f);
                    float r2 = fmaxf(v[2], 0.f), r3 = fmaxf(v[3], 0.f);
                    *(uint2*)&sm.a.H1[sw128(m, n0)] = make_uint2(pk2(r0,r1), pk2(r2,r3));
                }
            }
        }
        __syncthreads();

        // ===== L2': H2 = relu(W2^T · H1^T + b2) =====
        {
            f32x4 acc[2][4];
            #pragma unroll
            for (int jn = 0; jn < 2; ++jn) {
                f32x4 bias = *(const f32x4*)&B2F[chB + 16*jn + 4*l4];
                #pragma unroll
                for (int im = 0; im < 4; ++im) acc[jn][im] = bias;
            }
            #pragma unroll
            for (int kk = 0; kk < 4; ++kk)
                #pragma unroll
                for (int im = 0; im < 4; ++im) {
                    short8 bfr = *(const short8*)&sm.a.H1[sw128(smB + 16*im + l15, kk*32 + 8*l4)];
                    acc[0][im] = MFMA16(w2f[0][kk], bfr, acc[0][im]);
                    acc[1][im] = MFMA16(w2f[1][kk], bfr, acc[1][im]);
                }
            #pragma unroll
            for (int jn = 0; jn < 2; ++jn)
                #pragma unroll
                for (int im = 0; im < 4; ++im) {
                    int m  = smB + 16*im + l15;
                    int n0 = chB + 16*jn + 4*l4;
                    f32x4 v = acc[jn][im];
                    float r0 = fmaxf(v[0], 0.f), r1 = fmaxf(v[1], 0.f);
                    float r2 = fmaxf(v[2], 0.f), r3 = fmaxf(v[3], 0.f);
                    *(uint2*)&sm.a.H2[sw128(m, n0)] = make_uint2(pk2(r0,r1), pk2(r2,r3));
                }
        }
        __syncthreads();

        // ===== G3': feat(+bf) -> CC[:,0:16], sigma-dot -> CS[3][:] =====
        {
            f32x4 f30 = bfv;
            f32x4 f31 = (f32x4){0.f,0.f,0.f,0.f};
            const int m = sB3 + l15;
            #pragma unroll
            for (int kk = 0; kk < 4; ++kk) {
                short8 bA = *(const short8*)&sm.a.H2[sw128(m, kk*32 + 8*l4)];
                short8 wfd0 = *(const short8*)&Wfd17[sw128(l15, kk*32 + 8*l4)];
                short8 wfd1 = z8;
                if (l15 == 0) wfd1 = *(const short8*)&Wfd17[sw128(16, kk*32 + 8*l4)];
                f30 = MFMA16(wfd0, bA, f30);
                f31 = MFMA16(wfd1, bA, f31);
            }
            *(uint2*)&sm.a.CC[m*CSTR + 4*l4] = make_uint2(pk2(f30[0],f30[1]), pk2(f30[2],f30[3]));
            if (l4 == 0) sm.a.CS[3*128 + m] = f31[0];
        }
        __syncthreads();

        // ===== G4': HC = relu(Wc1^T · [feat|ynm]^T + bc1) -> H1 =====
        {
            short8 bcc[4];
            #pragma unroll
            for (int sg = 0; sg < 4; ++sg) {
                int m = smB + 16*sg + l15;
                if (l4 < 2) bcc[sg] = *(const short8*)&sm.a.CC[m*CSTR + 8*l4];
                else        bcc[sg] = *(const short8*)&sm.a.CC[((m >> 6)*64 + (l4 - 2))*CSTR + 16];
            }
            #pragma unroll
            for (int cg = 0; cg < 2; ++cg) {
                f32x4 bias = *(const f32x4*)&BC1F[chB + 16*cg + 4*l4];
                #pragma unroll
                for (int sg = 0; sg < 4; ++sg) {
                    f32x4 v = MFMA16(wc1f[cg], bcc[sg], bias);
                    int m  = smB + 16*sg + l15;
                    int n0 = chB + 16*cg + 4*l4;
                    float r0 = fmaxf(v[0], 0.f), r1 = fmaxf(v[1], 0.f);
                    float r2 = fmaxf(v[2], 0.f), r3 = fmaxf(v[3], 0.f);
                    *(uint2*)&sm.a.H1[sw128(m, n0)] = make_uint2(pk2(r0,r1), pk2(r2,r3));
                }
            }
        }
        __syncthreads();

        // ===== G5': color = sigmoid(Wc2^T · HC^T + bc2) -> CS[0..2][:] =====
        {
            f32x4 c5 = (f32x4){0.f,0.f,0.f,0.f};
            const int m = sB3 + l15;
            #pragma unroll
            for (int kk = 0; kk < 4; ++kk) {
                short8 wc2fr = z8;
                if (l15 < 3) wc2fr = *(const short8*)&Wc2T3[l15*128 + kk*32 + 8*l4];
                short8 b = *(const short8*)&sm.a.H1[sw128(m, kk*32 + 8*l4)];
                c5 = MFMA16(wc2fr, b, c5);
            }
            if (l4 == 0) {
                #pragma unroll
                for (int vv = 0; vv < 3; ++vv)
                    sm.a.CS[vv*128 + m] = 1.f / (1.f + __expf(-(c5[vv] + bc2r[vv])));
            }
        }
        __syncthreads();

        gp = g;
    }

    // trailing F for the last iteration
    if (gp >= 0 && wv < 2) {
        RayP R = raySetup(rays_o, rays_d, 2*gp + wv, a0x,a0y,a0z,a1x,a1y,a1z);
        const int m = wv*64 + lane;
        float t  = R.tn + ((float)lane + 0.5f) * R.tstep;
        float px = fmaf(R.dx, t, R.ox);
        float py = fmaf(R.dy, t, R.oy);
        float pz = fmaf(R.dz, t, R.oz);
        float nx = fmaf(px - a0x, scx, -1.f);
        float ny = fmaf(py - a0y, scy, -1.f);
        float nz = fmaf(pz - a0z, scz, -1.f);
        bool ins = (nx >= -1.f) & (nx <= 1.f) & (ny >= -1.f) & (ny <= 1.f)
                 & (nz >= -1.f) & (nz <= 1.f);
        float sig = ins ? __expf(sm.a.CS[3*128 + m] + bdr) : 0.f;
        float delta = (lane == 63) ? (R.tf + 1.0f - t) : R.tstep;
        float tau = sig * delta * R.dnorm;
        float cum = tau;
        #pragma unroll
        for (int off = 1; off < 64; off <<= 1) {
            float tmp = __shfl_up(cum, off);
            if (lane >= off) cum += tmp;
        }
        float excl = cum - tau;
        float wgt = __expf(-excl) * (1.f - __expf(-tau));
        float c0 = wgt * sm.a.CS[0*128 + m];
        float c1 = wgt * sm.a.CS[1*128 + m];
        float c2 = wgt * sm.a.CS[2*128 + m];
        float amv = wgt;
        float dmv = wgt * t;
        #pragma unroll
        for (int off = 32; off; off >>= 1) {
            c0  += __shfl_xor(c0,  off);
            c1  += __shfl_xor(c1,  off);
            c2  += __shfl_xor(c2,  off);
            amv += __shfl_xor(amv, off);
            dmv += __shfl_xor(dmv, off);
        }
        if (lane == 0) {
            float msk = R.act ? 1.f : 0.f;
            int ray = 2*gp + wv;
            out[ray*5+0] = c0*msk;
            out[ray*5+1] = c1*msk;
            out[ray*5+2] = c2*msk;
            out[ray*5+3] = amv*msk;
            out[ray*5+4] = dmv*msk;
        }
    }
}

extern "C" void kernel_launch(void* const* d_in, const int* in_sizes, int n_in,
                              void* d_out, int out_size, void* d_ws, size_t ws_size,
                              hipStream_t stream) {
    (void)in_sizes; (void)n_in; (void)d_ws; (void)ws_size; (void)out_size;
    const float* rays_o = (const float*)d_in[0];
    const float* rays_d = (const float*)d_in[1];
    const float* aabb   = (const float*)d_in[2];
    const float* W1  = (const float*)d_in[3];
    const float* b1  = (const float*)d_in[4];
    const float* W2  = (const float*)d_in[5];
    const float* b2  = (const float*)d_in[6];
    const float* Wd  = (const float*)d_in[7];
    const float* bd  = (const float*)d_in[8];
    const float* Wf  = (const float*)d_in[9];
    const float* bf  = (const float*)d_in[10];
    const float* Wc1 = (const float*)d_in[11];
    const float* bc1 = (const float*)d_in[12];
    const float* Wc2 = (const float*)d_in[13];
    const float* bc2 = (const float*)d_in[14];
    float* out = (float*)d_out;

    hipLaunchKernelGGL(RadianceRenderer_kernel, dim3(GRID), dim3(THREADS), 0, stream,
                       rays_o, rays_d, aabb, W1, b1, W2, b2, Wd, bd,
                       Wf, bf, Wc1, bc1, Wc2, bc2, out);
}